// Round 2
// baseline (403.351 us; speedup 1.0000x reference)
//
#include <hip/hip_runtime.h>
#include <hip/hip_bf16.h>

// ---------------------------------------------------------------------------
// PolygonPredictionLayer: B=8,P=64,N=512,T=196(->224),S=100(->112),C=256,H=8,dh=32
// Pipeline:
//   prep      : weights f32->bf16 into ws, zero qcp pad
//   gemm G1   : qkv_s = qf @ [wq_s;wk_s;wv_s]^T  (A read strided from query_features)
//   self_attn : per (b,h) VALU attention -> sav
//   gemm G2   : osb = sav @ wo_s^T + bo_s
//   gemm G3   : qcp = (osb @ wq_c^T + bq_c)*scale   (padded (b,h,112,32) bf16)
//   kvproj    : kcT[n][c][224], vc[n][224][c]  bf16 (t>=196 masked later)
//   attn_fuse : per proposal: flash attn (wave=head) + wo_c + relu(w1) + heads
// Round-2 fix: uint4 = 8 ushorts (16B), not 16 — all B/KC/VC staging sites now
// issue 2x uint4 per thread so the full 32-ushort span is written.
// ---------------------------------------------------------------------------

typedef __attribute__((ext_vector_type(8))) short bf16x8;
typedef __attribute__((ext_vector_type(4))) float f32x4;

__device__ __forceinline__ float bf2f(ushort u) {
    union { float f; uint u32; } v; v.u32 = ((uint)u) << 16; return v.f;
}
__device__ __forceinline__ ushort f2bf(float f) {
    union { float f; uint u; } v; v.f = f;
    uint r = v.u + 0x7FFF + ((v.u >> 16) & 1);
    return (ushort)(r >> 16);
}
__device__ __forceinline__ f32x4 MFMA(bf16x8 a, bf16x8 b, f32x4 c) {
    return __builtin_amdgcn_mfma_f32_16x16x32_bf16(a, b, c, 0, 0, 0);
}

#define SCALE_DH 0.17677669529663687f  // 1/sqrt(32)

// ---------------- prep: weights -> bf16, qcp zero ---------------------------
// row table: 0 wq_s,256 wk_s,512 wv_s,768 wo_s,1024 wq_c,1280 wk_c,1536 wv_c,
//            1792 wo_c,2048 w1,2304 w2(32),2336 ws(1)  -> 2337 rows x 256
#define TOTALW (2337 * 256)
#define QCPN   (8 * 8 * 112 * 32)

__global__ void prep_kernel(const float* w0, const float* w1_, const float* w2_,
                            const float* w3, const float* w4, const float* w5,
                            const float* w6, const float* w7, const float* w8,
                            const float* w9, const float* w10,
                            ushort* wbf, ushort* qcp)
{
    for (size_t i = blockIdx.x * blockDim.x + threadIdx.x;
         i < (size_t)TOTALW + QCPN; i += (size_t)gridDim.x * blockDim.x) {
        if (i < TOTALW) {
            int row = (int)(i >> 8), col = (int)(i & 255);
            const float* sp; int base;
            if      (row < 256)  { sp = w0;  base = 0; }
            else if (row < 512)  { sp = w1_; base = 256; }
            else if (row < 768)  { sp = w2_; base = 512; }
            else if (row < 1024) { sp = w3;  base = 768; }
            else if (row < 1280) { sp = w4;  base = 1024; }
            else if (row < 1536) { sp = w5;  base = 1280; }
            else if (row < 1792) { sp = w6;  base = 1536; }
            else if (row < 2048) { sp = w7;  base = 1792; }
            else if (row < 2304) { sp = w8;  base = 2048; }
            else if (row < 2336) { sp = w9;  base = 2304; }
            else                 { sp = w10; base = 2336; }
            wbf[i] = f2bf(sp[(size_t)(row - base) * 256 + col]);
        } else {
            qcp[i - TOTALW] = 0;
        }
    }
}

// ---------------- generic small GEMM: out = A @ W^T + bias -----------------
// block 256 thr (4 waves), tile 64(M) x 128(N), K=256 in 8 steps of 32.
// ASRC 0: A bf16 row-major [r][256].  ASRC 1: A[r][c] = f32src[g*256*GS + c*GS + o]
// EPI  0: Out bf16 [r][ldo].          EPI  1: qcp layout ((b*8+h)*112+s)*32+d, *scale
template<int ASRC, int GS, int EPI>
__global__ __launch_bounds__(256)
void gemm_rows(const void* Aptr, const ushort* Wall, const float* Ball,
               ushort* Out, int M, int Wrow0, int Brow0, int ldo)
{
    __shared__ ushort As[64 * 40];
    __shared__ ushort Bs[128 * 40];
    int tid = threadIdx.x;
    int lane = tid & 63, w = tid >> 6;
    int lr = lane & 15, lg = lane >> 4;
    int r0 = blockIdx.x * 64;
    int j0 = blockIdx.y * 128;

    f32x4 acc[4][2];
    #pragma unroll
    for (int mt = 0; mt < 4; ++mt)
        #pragma unroll
        for (int nt = 0; nt < 2; ++nt) { f32x4 z = {0.f,0.f,0.f,0.f}; acc[mt][nt] = z; }

    for (int ks = 0; ks < 8; ++ks) {
        int c0 = ks * 32;
        // stage A [64][40]: thread covers 8 ushorts (one uint4)
        {
            int i = tid >> 2, q = tid & 3;
            int r = r0 + i;
            if (ASRC == 0) {
                uint4 v = make_uint4(0u,0u,0u,0u);
                if (r < M) v = *(const uint4*)((const ushort*)Aptr + (size_t)r * 256 + c0 + q * 8);
                *(uint4*)(&As[i * 40 + q * 8]) = v;
            } else {
                uint u[4] = {0u,0u,0u,0u};
                if (r < M) {
                    int g = r / GS, o = r - g * GS;
                    const float* src = (const float*)Aptr + (size_t)g * 256 * GS + o;
                    #pragma unroll
                    for (int k2 = 0; k2 < 4; ++k2) {
                        ushort a0 = f2bf(src[(size_t)(c0 + q * 8 + 2 * k2)     * GS]);
                        ushort a1 = f2bf(src[(size_t)(c0 + q * 8 + 2 * k2 + 1) * GS]);
                        u[k2] = (uint)a0 | ((uint)a1 << 16);
                    }
                }
                *(uint4*)(&As[i * 40 + q * 8]) = make_uint4(u[0], u[1], u[2], u[3]);
            }
        }
        // stage B [128][40]: thread covers 16 ushorts -> TWO uint4
        {
            int jj = tid >> 1, half = tid & 1;
            const ushort* src = Wall + (size_t)(Wrow0 + j0 + jj) * 256 + c0 + half * 16;
            ushort* dst = &Bs[jj * 40 + half * 16];
            *(uint4*)(dst)     = *(const uint4*)(src);
            *(uint4*)(dst + 8) = *(const uint4*)(src + 8);
        }
        __syncthreads();
        bf16x8 bfr[2];
        #pragma unroll
        for (int nt = 0; nt < 2; ++nt)
            bfr[nt] = *(const bf16x8*)(&Bs[(w * 32 + nt * 16 + lr) * 40 + lg * 8]);
        #pragma unroll
        for (int mt = 0; mt < 4; ++mt) {
            bf16x8 afr = *(const bf16x8*)(&As[(mt * 16 + lr) * 40 + lg * 8]);
            acc[mt][0] = MFMA(afr, bfr[0], acc[mt][0]);
            acc[mt][1] = MFMA(afr, bfr[1], acc[mt][1]);
        }
        __syncthreads();
    }
    // epilogue
    #pragma unroll
    for (int mt = 0; mt < 4; ++mt) {
        #pragma unroll
        for (int nt = 0; nt < 2; ++nt) {
            int jc = j0 + w * 32 + nt * 16 + lr;
            float bias = Ball[Brow0 + jc];
            #pragma unroll
            for (int rg = 0; rg < 4; ++rg) {
                int r = r0 + mt * 16 + lg * 4 + rg;
                if (r >= M) continue;
                float vv = acc[mt][nt][rg] + bias;
                if (EPI == 0) {
                    Out[(size_t)r * ldo + jc] = f2bf(vv);
                } else {
                    int b = r / 100, s = r - b * 100;
                    int h = jc >> 5, d = jc & 31;
                    Out[(((size_t)(b * 8 + h)) * 112 + s) * 32 + d] = f2bf(vv * SCALE_DH);
                }
            }
        }
    }
}

// ---------------- self-attention (tiny, VALU) ------------------------------
__global__ __launch_bounds__(128)
void self_attn(const ushort* qkv, ushort* sav)
{
    __shared__ float kls[100][33];
    __shared__ float vls[100][33];
    __shared__ float sls[100][101];
    int bh = blockIdx.x; int b = bh >> 3, h = bh & 7;
    int tid = threadIdx.x;
    for (int idx = tid; idx < 100 * 32; idx += 128) {
        int t = idx >> 5, d = idx & 31;
        kls[t][d] = bf2f(qkv[((size_t)(b * 100 + t)) * 768 + 256 + h * 32 + d]);
        vls[t][d] = bf2f(qkv[((size_t)(b * 100 + t)) * 768 + 512 + h * 32 + d]);
    }
    __syncthreads();
    if (tid < 100) {
        int s = tid;
        float q[32];
        #pragma unroll
        for (int d = 0; d < 32; ++d)
            q[d] = bf2f(qkv[((size_t)(b * 100 + s)) * 768 + h * 32 + d]) * SCALE_DH;
        float mx = -1e30f;
        for (int t = 0; t < 100; ++t) {
            float sc = 0.f;
            #pragma unroll
            for (int d = 0; d < 32; ++d) sc += q[d] * kls[t][d];
            sls[s][t] = sc; mx = fmaxf(mx, sc);
        }
        float sum = 0.f;
        for (int t = 0; t < 100; ++t) {
            float p = __expf(sls[s][t] - mx);
            sls[s][t] = p; sum += p;
        }
        float inv = 1.f / sum;
        float acc2[32];
        #pragma unroll
        for (int d = 0; d < 32; ++d) acc2[d] = 0.f;
        for (int t = 0; t < 100; ++t) {
            float pv = sls[s][t];
            #pragma unroll
            for (int d = 0; d < 32; ++d) acc2[d] += pv * vls[t][d];
        }
        #pragma unroll
        for (int d = 0; d < 32; ++d)
            sav[((size_t)(b * 100 + s)) * 256 + h * 32 + d] = f2bf(acc2[d] * inv);
    }
}

// ---------------- kvproj: kcT[n][c][224], vc[n][224][c] --------------------
// grid (cnt, jt 0..1, th 0..1), block 512 (8 waves), tile 112(t) x 256(j), K=256
__global__ __launch_bounds__(512)
void kvproj(const float* features, const ushort* Wall, const float* Ball,
            ushort* kc, ushort* vc, int n_base)
{
    __shared__ ushort As[112 * 40];
    __shared__ ushort Bs[256 * 40];
    int tid = threadIdx.x;
    int lane = tid & 63, w = tid >> 6;
    int lr = lane & 15, lg = lane >> 4;
    int nl = blockIdx.x;
    int n  = n_base + nl;
    int jt = blockIdx.y;        // 0: kc, 1: vc
    int th = blockIdx.z;
    int t0 = th * 112;
    const float* fb = features + (size_t)n * 256 * 196;
    int jbase = jt * 256;

    f32x4 acc[7][2];
    #pragma unroll
    for (int mt = 0; mt < 7; ++mt)
        #pragma unroll
        for (int nt = 0; nt < 2; ++nt) { f32x4 z = {0.f,0.f,0.f,0.f}; acc[mt][nt] = z; }

    for (int ks = 0; ks < 8; ++ks) {
        int c0 = ks * 32;
        {   // stage A: feats^T chunk [112 t][32 c]
            int cc = tid >> 4, tg = tid & 15;
            #pragma unroll
            for (int k2 = 0; k2 < 7; ++k2) {
                int t = tg * 7 + k2;
                int tgl = t0 + t;
                ushort v = 0;
                if (tgl < 196) v = f2bf(fb[(size_t)(c0 + cc) * 196 + tgl]);
                As[t * 40 + cc] = v;
            }
        }
        {   // stage B: Wkv rows [jbase..jbase+255], thread covers 16 ushorts
            int jj = tid >> 1, half = tid & 1;
            const ushort* src = Wall + (size_t)(1280 + jbase + jj) * 256 + c0 + half * 16;
            ushort* dst = &Bs[jj * 40 + half * 16];
            *(uint4*)(dst)     = *(const uint4*)(src);
            *(uint4*)(dst + 8) = *(const uint4*)(src + 8);
        }
        __syncthreads();
        bf16x8 bfr[2];
        #pragma unroll
        for (int nt = 0; nt < 2; ++nt)
            bfr[nt] = *(const bf16x8*)(&Bs[(w * 32 + nt * 16 + lr) * 40 + lg * 8]);
        #pragma unroll
        for (int mt = 0; mt < 7; ++mt) {
            bf16x8 afr = *(const bf16x8*)(&As[(mt * 16 + lr) * 40 + lg * 8]);
            acc[mt][0] = MFMA(afr, bfr[0], acc[mt][0]);
            acc[mt][1] = MFMA(afr, bfr[1], acc[mt][1]);
        }
        __syncthreads();
    }
    #pragma unroll
    for (int mt = 0; mt < 7; ++mt) {
        #pragma unroll
        for (int nt = 0; nt < 2; ++nt) {
            int jj = w * 32 + nt * 16 + lr;
            float bias = Ball[1280 + jbase + jj];
            if (jt == 0) {
                size_t base = ((size_t)nl * 256 + jj) * 224 + t0 + mt * 16 + lg * 4;
                uint v01 = (uint)f2bf(acc[mt][nt][0] + bias) | ((uint)f2bf(acc[mt][nt][1] + bias) << 16);
                uint v23 = (uint)f2bf(acc[mt][nt][2] + bias) | ((uint)f2bf(acc[mt][nt][3] + bias) << 16);
                *(uint*)(kc + base)     = v01;
                *(uint*)(kc + base + 2) = v23;
            } else {
                size_t base = ((size_t)nl * 224 + t0 + mt * 16 + lg * 4) * 256 + jj;
                #pragma unroll
                for (int rg = 0; rg < 4; ++rg)
                    vc[base + (size_t)rg * 256] = f2bf(acc[mt][nt][rg] + bias);
            }
        }
    }
}

// ---------------- fused cross-attn + heads, one block per proposal ---------
// block 512 (8 waves, wave = head). LDS: buf1 71680 (P[8][112][40] -> o/h1 [112][264])
//                                   buf2 59136 (kc[256][40]+vc[32][264] -> o2 [112][264])
__global__ __launch_bounds__(512)
void attn_fuse(const ushort* qcp, const ushort* kc, const ushort* vc,
               const ushort* Wall, const float* Ball, float* outp, int n_base)
{
    __shared__ char smem[71680 + 59136];
    ushort* P   = (ushort*)smem;                       // [8][112][40]
    ushort* KCs = (ushort*)(smem + 71680);             // [256][40]
    ushort* VCs = (ushort*)(smem + 71680 + 20480);     // [32][264]
    ushort* OL  = (ushort*)smem;                       // [112][264] (o, then h1)
    ushort* O2  = (ushort*)(smem + 71680);             // [112][264]
    float* hbar = (float*)(smem + 59392);              // 256 f32 (buf1 spare)
    float* scb  = (float*)(smem + 60416);              // 112 f32

    int tid = threadIdx.x;
    int lane = tid & 63; int w = tid >> 6;             // w = head
    int lr = lane & 15, lg = lane >> 4;
    int nl = blockIdx.x; int n = n_base + nl;
    int b = n >> 6;
    const ushort* kcn = kc + (size_t)nl * 256 * 224;
    const ushort* vcn = vc + (size_t)nl * 224 * 256;

    bf16x8 qf[7];
    #pragma unroll
    for (int mt = 0; mt < 7; ++mt)
        qf[mt] = *(const bf16x8*)(qcp + ((((size_t)(b * 8 + w)) * 112 + mt * 16 + lr) * 32 + lg * 8));

    f32x4 o_acc[7][2];
    float m_st[7][4], l_st[7][4];
    #pragma unroll
    for (int mt = 0; mt < 7; ++mt) {
        #pragma unroll
        for (int nt = 0; nt < 2; ++nt) { f32x4 z = {0.f,0.f,0.f,0.f}; o_acc[mt][nt] = z; }
        #pragma unroll
        for (int r = 0; r < 4; ++r) { m_st[mt][r] = -1e30f; l_st[mt][r] = 0.f; }
    }

    for (int ch = 0; ch < 7; ++ch) {
        int t0 = ch * 32;
        __syncthreads();   // protect prior-chunk reads of KCs/VCs
        {   // stage kcT chunk [256][32] -> stride 40; thread covers 16 ushorts
            int c = tid >> 1, hf = tid & 1;
            const ushort* src = kcn + (size_t)c * 224 + t0 + hf * 16;
            ushort* dst = &KCs[c * 40 + hf * 16];
            *(uint4*)(dst)     = *(const uint4*)(src);
            *(uint4*)(dst + 8) = *(const uint4*)(src + 8);
        }
        {   // stage vc chunk [32][256] -> stride 264; thread covers 16 ushorts
            int tt = tid >> 4, seg = tid & 15;
            const ushort* src = vcn + ((size_t)(t0 + tt)) * 256 + seg * 16;
            ushort* dst = &VCs[tt * 264 + seg * 16];
            *(uint4*)(dst)     = *(const uint4*)(src);
            *(uint4*)(dst + 8) = *(const uint4*)(src + 8);
        }
        __syncthreads();

        // QK^T B-frags
        bf16x8 bk[2];
        #pragma unroll
        for (int nt = 0; nt < 2; ++nt) {
            bf16x8 tv;
            #pragma unroll
            for (int j = 0; j < 8; ++j)
                tv[j] = (short)KCs[(w * 32 + lg * 8 + j) * 40 + nt * 16 + lr];
            bk[nt] = tv;
        }
        bool mask0 = (t0 + lr)      >= 196;
        bool mask1 = (t0 + 16 + lr) >= 196;
        #pragma unroll
        for (int mt = 0; mt < 7; ++mt) {
            f32x4 z = {0.f,0.f,0.f,0.f};
            f32x4 s0v = MFMA(qf[mt], bk[0], z);
            f32x4 s1v = MFMA(qf[mt], bk[1], z);
            #pragma unroll
            for (int r = 0; r < 4; ++r) {
                float sc0 = mask0 ? -1e30f : s0v[r];
                float sc1 = mask1 ? -1e30f : s1v[r];
                float rm = fmaxf(sc0, sc1);
                rm = fmaxf(rm, __shfl_xor(rm, 1));
                rm = fmaxf(rm, __shfl_xor(rm, 2));
                rm = fmaxf(rm, __shfl_xor(rm, 4));
                rm = fmaxf(rm, __shfl_xor(rm, 8));
                float mold = m_st[mt][r];
                float mnew = fmaxf(mold, rm);
                float fac = __expf(mold - mnew);
                float p0 = __expf(sc0 - mnew);
                float p1 = __expf(sc1 - mnew);
                float rs = p0 + p1;
                rs += __shfl_xor(rs, 1);
                rs += __shfl_xor(rs, 2);
                rs += __shfl_xor(rs, 4);
                rs += __shfl_xor(rs, 8);
                l_st[mt][r] = l_st[mt][r] * fac + rs;
                m_st[mt][r] = mnew;
                o_acc[mt][0][r] *= fac;
                o_acc[mt][1][r] *= fac;
                int srow = mt * 16 + lg * 4 + r;
                P[(w * 112 + srow) * 40 + lr]      = f2bf(p0);
                P[(w * 112 + srow) * 40 + 16 + lr] = f2bf(p1);
            }
        }
        // PV (wave-local P; compiler orders ds ops)
        bf16x8 bv[2];
        #pragma unroll
        for (int nt = 0; nt < 2; ++nt) {
            bf16x8 tv;
            #pragma unroll
            for (int j = 0; j < 8; ++j)
                tv[j] = (short)VCs[(lg * 8 + j) * 264 + w * 32 + nt * 16 + lr];
            bv[nt] = tv;
        }
        #pragma unroll
        for (int mt = 0; mt < 7; ++mt) {
            bf16x8 pf = *(const bf16x8*)(&P[(w * 112 + mt * 16 + lr) * 40 + lg * 8]);
            o_acc[mt][0] = MFMA(pf, bv[0], o_acc[mt][0]);
            o_acc[mt][1] = MFMA(pf, bv[1], o_acc[mt][1]);
        }
    }

    __syncthreads();   // P dead; write normalized O into buf1 as [112][264]
    #pragma unroll
    for (int mt = 0; mt < 7; ++mt)
        #pragma unroll
        for (int nt = 0; nt < 2; ++nt)
            #pragma unroll
            for (int r = 0; r < 4; ++r) {
                int srow = mt * 16 + lg * 4 + r;
                float v = o_acc[mt][nt][r] / l_st[mt][r];
                OL[srow * 264 + w * 32 + nt * 16 + lr] = f2bf(v);
            }
    __syncthreads();

    // o2 = OL @ wo_c^T + bo_c   (wave w owns cols [32w,32w+32))
    {
        f32x4 a2[7][2];
        #pragma unroll
        for (int mt = 0; mt < 7; ++mt)
            #pragma unroll
            for (int nt = 0; nt < 2; ++nt) { f32x4 z = {0.f,0.f,0.f,0.f}; a2[mt][nt] = z; }
        for (int ks = 0; ks < 8; ++ks) {
            int c0 = ks * 32;
            bf16x8 bw[2];
            #pragma unroll
            for (int nt = 0; nt < 2; ++nt)
                bw[nt] = *(const bf16x8*)(Wall + (size_t)(1792 + w * 32 + nt * 16 + lr) * 256 + c0 + lg * 8);
            #pragma unroll
            for (int mt = 0; mt < 7; ++mt) {
                bf16x8 af = *(const bf16x8*)(&OL[(mt * 16 + lr) * 264 + c0 + lg * 8]);
                a2[mt][0] = MFMA(af, bw[0], a2[mt][0]);
                a2[mt][1] = MFMA(af, bw[1], a2[mt][1]);
            }
        }
        #pragma unroll
        for (int mt = 0; mt < 7; ++mt)
            #pragma unroll
            for (int nt = 0; nt < 2; ++nt) {
                float bias = Ball[1792 + w * 32 + nt * 16 + lr];
                #pragma unroll
                for (int r = 0; r < 4; ++r) {
                    int srow = mt * 16 + lg * 4 + r;
                    O2[srow * 264 + w * 32 + nt * 16 + lr] = f2bf(a2[mt][nt][r] + bias);
                }
            }
    }
    __syncthreads();

    // h1 = relu(O2 @ w1^T + b1) -> OL
    {
        f32x4 a2[7][2];
        #pragma unroll
        for (int mt = 0; mt < 7; ++mt)
            #pragma unroll
            for (int nt = 0; nt < 2; ++nt) { f32x4 z = {0.f,0.f,0.f,0.f}; a2[mt][nt] = z; }
        for (int ks = 0; ks < 8; ++ks) {
            int c0 = ks * 32;
            bf16x8 bw[2];
            #pragma unroll
            for (int nt = 0; nt < 2; ++nt)
                bw[nt] = *(const bf16x8*)(Wall + (size_t)(2048 + w * 32 + nt * 16 + lr) * 256 + c0 + lg * 8);
            #pragma unroll
            for (int mt = 0; mt < 7; ++mt) {
                bf16x8 af = *(const bf16x8*)(&O2[(mt * 16 + lr) * 264 + c0 + lg * 8]);
                a2[mt][0] = MFMA(af, bw[0], a2[mt][0]);
                a2[mt][1] = MFMA(af, bw[1], a2[mt][1]);
            }
        }
        __syncthreads();   // all OL reads (oproj) finished before overwrite
        #pragma unroll
        for (int mt = 0; mt < 7; ++mt)
            #pragma unroll
            for (int nt = 0; nt < 2; ++nt) {
                float bias = Ball[2048 + w * 32 + nt * 16 + lr];
                #pragma unroll
                for (int r = 0; r < 4; ++r) {
                    int srow = mt * 16 + lg * 4 + r;
                    float v = a2[mt][nt][r] + bias;
                    v = v > 0.f ? v : 0.f;
                    OL[srow * 264 + w * 32 + nt * 16 + lr] = f2bf(v);
                }
            }
    }
    __syncthreads();

    // hbar[c] = mean_s<100 h1[s][c];  score partials from O2
    if (tid < 256) {
        float s = 0.f;
        for (int srow = 0; srow < 100; ++srow) s += bf2f(OL[srow * 264 + tid]);
        hbar[tid] = s * 0.01f;
    }
    if (tid < 100) {
        float s = 0.f;
        for (int c2 = 0; c2 < 256; ++c2)
            s += bf2f(O2[tid * 264 + c2]) * bf2f(Wall[(size_t)2336 * 256 + c2]);
        s += Ball[2336];
        scb[tid] = 1.f / (1.f + __expf(-s));
    }
    __syncthreads();
    if (tid < 32) {
        float s = 0.f;
        for (int c2 = 0; c2 < 256; ++c2)
            s += hbar[c2] * bf2f(Wall[(size_t)(2304 + tid) * 256 + c2]);
        s += Ball[2304 + tid];
        outp[(size_t)n * 32 + tid] = s;
    }
    if (tid == 64) {
        float s = 0.f;
        for (int i2 = 0; i2 < 100; ++i2) s += scb[i2];
        outp[16384 + n] = s * 0.01f;
    }
}

// ---------------------------------------------------------------------------
extern "C" void kernel_launch(void* const* d_in, const int* in_sizes, int n_in,
                              void* d_out, int out_size, void* d_ws, size_t ws_size,
                              hipStream_t stream)
{
    const float* features = (const float*)d_in[0];
    const float* qfeat    = (const float*)d_in[1];
    char* ws = (char*)d_ws;

    ushort* wbf  = (ushort*)ws;                    //  2337*256 bf16
    float*  bias = (float*)(ws + 1196544);         //  2337 f32
    ushort* qkv  = (ushort*)(ws + 1206016);        //  800*768
    ushort* sav  = (ushort*)(ws + 2434816);        //  800*256
    ushort* osb  = (ushort*)(ws + 2844416);        //  800*256
    ushort* qcp  = (ushort*)(ws + 3254016);        //  8*8*112*32
    ushort* kvb  = (ushort*)(ws + 3712768);

    // biases -> concat f32 table
    const int bi_idx[11] = {5, 6, 7, 9, 13, 14, 15, 17, 19, 21, 23};
    const int bi_off[11] = {0, 256, 512, 768, 1024, 1280, 1536, 1792, 2048, 2304, 2336};
    const int bi_sz [11] = {256, 256, 256, 256, 256, 256, 256, 256, 256, 32, 1};
    for (int i = 0; i < 11; ++i)
        hipMemcpyAsync(bias + bi_off[i], d_in[bi_idx[i]], (size_t)bi_sz[i] * 4,
                       hipMemcpyDeviceToDevice, stream);

    prep_kernel<<<dim3(512), dim3(256), 0, stream>>>(
        (const float*)d_in[2], (const float*)d_in[3], (const float*)d_in[4],
        (const float*)d_in[8], (const float*)d_in[10], (const float*)d_in[11],
        (const float*)d_in[12], (const float*)d_in[16], (const float*)d_in[18],
        (const float*)d_in[20], (const float*)d_in[22], wbf, qcp);

    // self-attention chain
    gemm_rows<1, 100, 0><<<dim3(13, 6), dim3(256), 0, stream>>>(
        qfeat, wbf, bias, qkv, 800, 0, 0, 768);
    self_attn<<<dim3(64), dim3(128), 0, stream>>>(qkv, sav);
    gemm_rows<0, 1, 0><<<dim3(13, 2), dim3(256), 0, stream>>>(
        sav, wbf, bias, osb, 800, 768, 768, 256);
    gemm_rows<0, 1, 1><<<dim3(13, 2), dim3(256), 0, stream>>>(
        osb, wbf, bias, qcp, 800, 1024, 1024, 0);

    // cross-attention, pass-split on workspace budget
    const size_t per_n = 229376;               // bytes of kc+vc per proposal
    long avail = (long)ws_size - 3712768L;
    int Np = 512;
    if (avail < (long)(per_n * 512)) {
        Np = (int)(avail / (long)per_n);
        if (Np < 1) Np = 1;
    }
    ushort* kcb = kvb;
    ushort* vcb = kvb + (size_t)Np * 256 * 224;
    float* outp = (float*)d_out;
    for (int n0 = 0; n0 < 512; n0 += Np) {
        int cnt = (512 - n0 < Np) ? (512 - n0) : Np;
        kvproj<<<dim3(cnt, 2, 2), dim3(512), 0, stream>>>(features, wbf, bias, kcb, vcb, n0);
        attn_fuse<<<dim3(cnt), dim3(512), 0, stream>>>(qcp, kcb, vcb, wbf, bias, outp, n0);
    }
}

// Round 3
// 270.956 us; speedup vs baseline: 1.4886x; 1.4886x over previous
//
#include <hip/hip_runtime.h>
#include <hip/hip_bf16.h>

// ---------------------------------------------------------------------------
// PolygonPredictionLayer: B=8,P=64,N=512,T=196(->224),S=100(->112),C=256,H=8,dh=32
// R3: (1) K global layout t-major [n][224][256], V c-major [n][256][224] so both
//     MFMA B-frags are single ds_read_b128; (2) no-max softmax + row-sum via
//     ones-MFMA (scores are O(1), f32 exp safe); (3) kvproj merges K+V in one
//     block (features read once); (4) biases folded into prep kernel.
// ---------------------------------------------------------------------------

typedef __attribute__((ext_vector_type(8))) short bf16x8;
typedef __attribute__((ext_vector_type(4))) float f32x4;

__device__ __forceinline__ float bf2f(ushort u) {
    union { float f; uint u32; } v; v.u32 = ((uint)u) << 16; return v.f;
}
__device__ __forceinline__ ushort f2bf(float f) {
    union { float f; uint u; } v; v.f = f;
    uint r = v.u + 0x7FFF + ((v.u >> 16) & 1);
    return (ushort)(r >> 16);
}
__device__ __forceinline__ f32x4 MFMA(bf16x8 a, bf16x8 b, f32x4 c) {
    return __builtin_amdgcn_mfma_f32_16x16x32_bf16(a, b, c, 0, 0, 0);
}

#define SCALE_DH 0.17677669529663687f  // 1/sqrt(32)

// ---------------- prep: weights+biases -> ws tables, qcp zero ---------------
// weight rows: 0 wq_s,256 wk_s,512 wv_s,768 wo_s,1024 wq_c,1280 wk_c,1536 wv_c,
//              1792 wo_c,2048 w1,2304 w2(32),2336 ws(1) -> 2337 rows x 256
#define TOTALW (2337 * 256)
#define QCPN   (8 * 8 * 112 * 32)
#define NBIAS  2337

__global__ void prep_kernel(const float* w0, const float* w1_, const float* w2_,
                            const float* w3, const float* w4, const float* w5,
                            const float* w6, const float* w7, const float* w8,
                            const float* w9, const float* w10,
                            const float* b0, const float* b1_, const float* b2_,
                            const float* b3, const float* b4, const float* b5,
                            const float* b6, const float* b7, const float* b8,
                            const float* b9, const float* b10,
                            ushort* wbf, float* bias, ushort* qcp)
{
    for (size_t i = blockIdx.x * blockDim.x + threadIdx.x;
         i < (size_t)TOTALW + QCPN + NBIAS; i += (size_t)gridDim.x * blockDim.x) {
        if (i < TOTALW) {
            int row = (int)(i >> 8), col = (int)(i & 255);
            const float* sp; int base;
            if      (row < 256)  { sp = w0;  base = 0; }
            else if (row < 512)  { sp = w1_; base = 256; }
            else if (row < 768)  { sp = w2_; base = 512; }
            else if (row < 1024) { sp = w3;  base = 768; }
            else if (row < 1280) { sp = w4;  base = 1024; }
            else if (row < 1536) { sp = w5;  base = 1280; }
            else if (row < 1792) { sp = w6;  base = 1536; }
            else if (row < 2048) { sp = w7;  base = 1792; }
            else if (row < 2304) { sp = w8;  base = 2048; }
            else if (row < 2336) { sp = w9;  base = 2304; }
            else                 { sp = w10; base = 2336; }
            wbf[i] = f2bf(sp[(size_t)(row - base) * 256 + col]);
        } else if (i < (size_t)TOTALW + QCPN) {
            qcp[i - TOTALW] = 0;
        } else {
            int idx = (int)(i - TOTALW - QCPN);
            const float* sp; int base;
            if      (idx < 256)  { sp = b0;  base = 0; }
            else if (idx < 512)  { sp = b1_; base = 256; }
            else if (idx < 768)  { sp = b2_; base = 512; }
            else if (idx < 1024) { sp = b3;  base = 768; }
            else if (idx < 1280) { sp = b4;  base = 1024; }
            else if (idx < 1536) { sp = b5;  base = 1280; }
            else if (idx < 1792) { sp = b6;  base = 1536; }
            else if (idx < 2048) { sp = b7;  base = 1792; }
            else if (idx < 2304) { sp = b8;  base = 2048; }
            else if (idx < 2336) { sp = b9;  base = 2304; }
            else                 { sp = b10; base = 2336; }
            bias[idx] = sp[idx - base];
        }
    }
}

// ---------------- generic small GEMM: out = A @ W^T + bias -----------------
template<int ASRC, int GS, int EPI>
__global__ __launch_bounds__(256)
void gemm_rows(const void* Aptr, const ushort* Wall, const float* Ball,
               ushort* Out, int M, int Wrow0, int Brow0, int ldo)
{
    __shared__ ushort As[64 * 40];
    __shared__ ushort Bs[128 * 40];
    int tid = threadIdx.x;
    int lane = tid & 63, w = tid >> 6;
    int lr = lane & 15, lg = lane >> 4;
    int r0 = blockIdx.x * 64;
    int j0 = blockIdx.y * 128;

    f32x4 acc[4][2];
    #pragma unroll
    for (int mt = 0; mt < 4; ++mt)
        #pragma unroll
        for (int nt = 0; nt < 2; ++nt) { f32x4 z = {0.f,0.f,0.f,0.f}; acc[mt][nt] = z; }

    for (int ks = 0; ks < 8; ++ks) {
        int c0 = ks * 32;
        {
            int i = tid >> 2, q = tid & 3;
            int r = r0 + i;
            if (ASRC == 0) {
                uint4 v = make_uint4(0u,0u,0u,0u);
                if (r < M) v = *(const uint4*)((const ushort*)Aptr + (size_t)r * 256 + c0 + q * 8);
                *(uint4*)(&As[i * 40 + q * 8]) = v;
            } else {
                uint u[4] = {0u,0u,0u,0u};
                if (r < M) {
                    int g = r / GS, o = r - g * GS;
                    const float* src = (const float*)Aptr + (size_t)g * 256 * GS + o;
                    #pragma unroll
                    for (int k2 = 0; k2 < 4; ++k2) {
                        ushort a0 = f2bf(src[(size_t)(c0 + q * 8 + 2 * k2)     * GS]);
                        ushort a1 = f2bf(src[(size_t)(c0 + q * 8 + 2 * k2 + 1) * GS]);
                        u[k2] = (uint)a0 | ((uint)a1 << 16);
                    }
                }
                *(uint4*)(&As[i * 40 + q * 8]) = make_uint4(u[0], u[1], u[2], u[3]);
            }
        }
        {
            int jj = tid >> 1, half = tid & 1;
            const ushort* src = Wall + (size_t)(Wrow0 + j0 + jj) * 256 + c0 + half * 16;
            ushort* dst = &Bs[jj * 40 + half * 16];
            *(uint4*)(dst)     = *(const uint4*)(src);
            *(uint4*)(dst + 8) = *(const uint4*)(src + 8);
        }
        __syncthreads();
        bf16x8 bfr[2];
        #pragma unroll
        for (int nt = 0; nt < 2; ++nt)
            bfr[nt] = *(const bf16x8*)(&Bs[(w * 32 + nt * 16 + lr) * 40 + lg * 8]);
        #pragma unroll
        for (int mt = 0; mt < 4; ++mt) {
            bf16x8 afr = *(const bf16x8*)(&As[(mt * 16 + lr) * 40 + lg * 8]);
            acc[mt][0] = MFMA(afr, bfr[0], acc[mt][0]);
            acc[mt][1] = MFMA(afr, bfr[1], acc[mt][1]);
        }
        __syncthreads();
    }
    #pragma unroll
    for (int mt = 0; mt < 4; ++mt) {
        #pragma unroll
        for (int nt = 0; nt < 2; ++nt) {
            int jc = j0 + w * 32 + nt * 16 + lr;
            float bias = Ball[Brow0 + jc];
            #pragma unroll
            for (int rg = 0; rg < 4; ++rg) {
                int r = r0 + mt * 16 + lg * 4 + rg;
                if (r >= M) continue;
                float vv = acc[mt][nt][rg] + bias;
                if (EPI == 0) {
                    Out[(size_t)r * ldo + jc] = f2bf(vv);
                } else {
                    int b = r / 100, s = r - b * 100;
                    int h = jc >> 5, d = jc & 31;
                    Out[(((size_t)(b * 8 + h)) * 112 + s) * 32 + d] = f2bf(vv * SCALE_DH);
                }
            }
        }
    }
}

// ---------------- self-attention (tiny, VALU) ------------------------------
__global__ __launch_bounds__(128)
void self_attn(const ushort* qkv, ushort* sav)
{
    __shared__ float kls[100][33];
    __shared__ float vls[100][33];
    __shared__ float sls[100][101];
    int bh = blockIdx.x; int b = bh >> 3, h = bh & 7;
    int tid = threadIdx.x;
    for (int idx = tid; idx < 100 * 32; idx += 128) {
        int t = idx >> 5, d = idx & 31;
        kls[t][d] = bf2f(qkv[((size_t)(b * 100 + t)) * 768 + 256 + h * 32 + d]);
        vls[t][d] = bf2f(qkv[((size_t)(b * 100 + t)) * 768 + 512 + h * 32 + d]);
    }
    __syncthreads();
    if (tid < 100) {
        int s = tid;
        float q[32];
        #pragma unroll
        for (int d = 0; d < 32; ++d)
            q[d] = bf2f(qkv[((size_t)(b * 100 + s)) * 768 + h * 32 + d]) * SCALE_DH;
        float mx = -1e30f;
        for (int t = 0; t < 100; ++t) {
            float sc = 0.f;
            #pragma unroll
            for (int d = 0; d < 32; ++d) sc += q[d] * kls[t][d];
            sls[s][t] = sc; mx = fmaxf(mx, sc);
        }
        float sum = 0.f;
        for (int t = 0; t < 100; ++t) {
            float p = __expf(sls[s][t] - mx);
            sls[s][t] = p; sum += p;
        }
        float inv = 1.f / sum;
        float acc2[32];
        #pragma unroll
        for (int d = 0; d < 32; ++d) acc2[d] = 0.f;
        for (int t = 0; t < 100; ++t) {
            float pv = sls[s][t];
            #pragma unroll
            for (int d = 0; d < 32; ++d) acc2[d] += pv * vls[t][d];
        }
        #pragma unroll
        for (int d = 0; d < 32; ++d)
            sav[((size_t)(b * 100 + s)) * 256 + h * 32 + d] = f2bf(acc2[d] * inv);
    }
}

// ---------------- kvproj: kc[n][224][256] (t-major), vcT[n][256][224] ------
// grid (cnt, th 0..1), block 512 (8 waves), tile 112(t) x 256(j) x2 outputs
__global__ __launch_bounds__(512)
void kvproj(const float* features, const ushort* Wall, const float* Ball,
            ushort* kc, ushort* vc, int n_base)
{
    __shared__ ushort As[112 * 40];
    __shared__ ushort Bk[256 * 40];
    __shared__ ushort Bv[256 * 40];
    int tid = threadIdx.x;
    int lane = tid & 63, w = tid >> 6;
    int lr = lane & 15, lg = lane >> 4;
    int nl = blockIdx.x;
    int n  = n_base + nl;
    int th = blockIdx.y;
    int t0 = th * 112;
    const float* fb = features + (size_t)n * 256 * 196;

    f32x4 ak[7][2], av[7][2];
    #pragma unroll
    for (int mt = 0; mt < 7; ++mt)
        #pragma unroll
        for (int nt = 0; nt < 2; ++nt) {
            f32x4 z = {0.f,0.f,0.f,0.f}; ak[mt][nt] = z; av[mt][nt] = z;
        }

    for (int ks = 0; ks < 8; ++ks) {
        int c0 = ks * 32;
        {   // stage A: feats^T chunk [112 t][32 c]
            int cc = tid >> 4, tg = tid & 15;
            #pragma unroll
            for (int k2 = 0; k2 < 7; ++k2) {
                int t = tg * 7 + k2;
                int tgl = t0 + t;
                ushort v = 0;
                if (tgl < 196) v = f2bf(fb[(size_t)(c0 + cc) * 196 + tgl]);
                As[t * 40 + cc] = v;
            }
        }
        {   // stage Bk (wk_c rows 1280..1535) and Bv (wv_c rows 1536..1791)
            int jj = tid >> 1, half = tid & 1;
            const ushort* srck = Wall + (size_t)(1280 + jj) * 256 + c0 + half * 16;
            const ushort* srcv = Wall + (size_t)(1536 + jj) * 256 + c0 + half * 16;
            ushort* dstk = &Bk[jj * 40 + half * 16];
            ushort* dstv = &Bv[jj * 40 + half * 16];
            *(uint4*)(dstk)     = *(const uint4*)(srck);
            *(uint4*)(dstk + 8) = *(const uint4*)(srck + 8);
            *(uint4*)(dstv)     = *(const uint4*)(srcv);
            *(uint4*)(dstv + 8) = *(const uint4*)(srcv + 8);
        }
        __syncthreads();
        bf16x8 bk2[2], bv2[2];
        #pragma unroll
        for (int nt = 0; nt < 2; ++nt) {
            bk2[nt] = *(const bf16x8*)(&Bk[(w * 32 + nt * 16 + lr) * 40 + lg * 8]);
            bv2[nt] = *(const bf16x8*)(&Bv[(w * 32 + nt * 16 + lr) * 40 + lg * 8]);
        }
        #pragma unroll
        for (int mt = 0; mt < 7; ++mt) {
            bf16x8 afr = *(const bf16x8*)(&As[(mt * 16 + lr) * 40 + lg * 8]);
            ak[mt][0] = MFMA(afr, bk2[0], ak[mt][0]);
            ak[mt][1] = MFMA(afr, bk2[1], ak[mt][1]);
            av[mt][0] = MFMA(afr, bv2[0], av[mt][0]);
            av[mt][1] = MFMA(afr, bv2[1], av[mt][1]);
        }
        __syncthreads();
    }
    #pragma unroll
    for (int mt = 0; mt < 7; ++mt) {
        #pragma unroll
        for (int nt = 0; nt < 2; ++nt) {
            int jj = w * 32 + nt * 16 + lr;
            float biask = Ball[1280 + jj];
            float biasv = Ball[1536 + jj];
            // kc t-major: kc[(nl*224 + t)*256 + jj]
            #pragma unroll
            for (int rg = 0; rg < 4; ++rg) {
                int t = t0 + mt * 16 + lg * 4 + rg;
                kc[((size_t)nl * 224 + t) * 256 + jj] = f2bf(ak[mt][nt][rg] + biask);
            }
            // vcT c-major: vc[(nl*256 + jj)*224 + t], packed pairs along t
            size_t vb = ((size_t)nl * 256 + jj) * 224 + t0 + mt * 16 + lg * 4;
            uint v01 = (uint)f2bf(av[mt][nt][0] + biasv) | ((uint)f2bf(av[mt][nt][1] + biasv) << 16);
            uint v23 = (uint)f2bf(av[mt][nt][2] + biasv) | ((uint)f2bf(av[mt][nt][3] + biasv) << 16);
            *(uint*)(vc + vb)     = v01;
            *(uint*)(vc + vb + 2) = v23;
        }
    }
}

// ---------------- fused cross-attn + heads, one block per proposal ---------
// block 512 (8 waves, wave = head).
// LDS: P[8][112][40] @0 (71680) | KCs[32][264] @71680 (16896) | VCs[256][40] @88576 (20480)
// epi: OL[112][264] @0 (59136) | O2[112][264] @71680 (59136) | hbar@59392 scb@60416
__global__ __launch_bounds__(512)
void attn_fuse(const ushort* qcp, const ushort* kc, const ushort* vc,
               const ushort* Wall, const float* Ball, float* outp, int n_base)
{
    __shared__ char smem[130816];
    ushort* P   = (ushort*)smem;
    ushort* KCs = (ushort*)(smem + 71680);
    ushort* VCs = (ushort*)(smem + 88576);
    ushort* OL  = (ushort*)smem;
    ushort* O2  = (ushort*)(smem + 71680);
    float* hbar = (float*)(smem + 59392);
    float* scb  = (float*)(smem + 60416);

    int tid = threadIdx.x;
    int lane = tid & 63; int w = tid >> 6;             // w = head
    int lr = lane & 15, lg = lane >> 4;
    int nl = blockIdx.x; int n = n_base + nl;
    int b = n >> 6;
    const ushort* kcn = kc + (size_t)nl * 224 * 256;
    const ushort* vcn = vc + (size_t)nl * 256 * 224;

    bf16x8 qf[7];
    #pragma unroll
    for (int mt = 0; mt < 7; ++mt)
        qf[mt] = *(const bf16x8*)(qcp + ((((size_t)(b * 8 + w)) * 112 + mt * 16 + lr) * 32 + lg * 8));

    bf16x8 ones;
    #pragma unroll
    for (int j = 0; j < 8; ++j) ones[j] = (short)0x3F80;   // bf16 1.0

    f32x4 o_acc[7][2], l_acc[7];
    #pragma unroll
    for (int mt = 0; mt < 7; ++mt) {
        f32x4 z = {0.f,0.f,0.f,0.f};
        o_acc[mt][0] = z; o_acc[mt][1] = z; l_acc[mt] = z;
    }

    for (int ch = 0; ch < 7; ++ch) {
        int t0 = ch * 32;
        __syncthreads();   // protect prior-chunk reads of KCs/VCs
        {   // stage K chunk [32 t][256 c] from kc t-major
            int tt = tid >> 4, seg = tid & 15;
            const ushort* src = kcn + ((size_t)(t0 + tt)) * 256 + seg * 16;
            ushort* dst = &KCs[tt * 264 + seg * 16];
            *(uint4*)(dst)     = *(const uint4*)(src);
            *(uint4*)(dst + 8) = *(const uint4*)(src + 8);
        }
        {   // stage V chunk [256 c][32 t] from vcT c-major
            int c = tid >> 1, half = tid & 1;
            const ushort* src = vcn + (size_t)c * 224 + t0 + half * 16;
            ushort* dst = &VCs[c * 40 + half * 16];
            *(uint4*)(dst)     = *(const uint4*)(src);
            *(uint4*)(dst + 8) = *(const uint4*)(src + 8);
        }
        __syncthreads();

        // QK^T: B-frag b[j] = K[t=nt*16+lr][d=w*32+lg*8+j] -- vector read
        bf16x8 bk[2];
        #pragma unroll
        for (int nt = 0; nt < 2; ++nt)
            bk[nt] = *(const bf16x8*)(&KCs[(nt * 16 + lr) * 264 + w * 32 + lg * 8]);
        bool mask0 = (t0 + lr)      >= 196;
        bool mask1 = (t0 + 16 + lr) >= 196;
        #pragma unroll
        for (int mt = 0; mt < 7; ++mt) {
            f32x4 z = {0.f,0.f,0.f,0.f};
            f32x4 s0v = MFMA(qf[mt], bk[0], z);
            f32x4 s1v = MFMA(qf[mt], bk[1], z);
            #pragma unroll
            for (int r = 0; r < 4; ++r) {
                float p0 = mask0 ? 0.f : __expf(s0v[r]);
                float p1 = mask1 ? 0.f : __expf(s1v[r]);
                int srow = mt * 16 + lg * 4 + r;
                P[(w * 112 + srow) * 40 + lr]      = f2bf(p0);
                P[(w * 112 + srow) * 40 + 16 + lr] = f2bf(p1);
            }
        }
        // PV: B-frag b[j] = V[t=lg*8+j][c=w*32+nt*16+lr] -- vector read
        bf16x8 bv[2];
        #pragma unroll
        for (int nt = 0; nt < 2; ++nt)
            bv[nt] = *(const bf16x8*)(&VCs[(w * 32 + nt * 16 + lr) * 40 + lg * 8]);
        #pragma unroll
        for (int mt = 0; mt < 7; ++mt) {
            bf16x8 pf = *(const bf16x8*)(&P[(w * 112 + mt * 16 + lr) * 40 + lg * 8]);
            o_acc[mt][0] = MFMA(pf, bv[0], o_acc[mt][0]);
            o_acc[mt][1] = MFMA(pf, bv[1], o_acc[mt][1]);
            l_acc[mt]    = MFMA(pf, ones,  l_acc[mt]);   // row sums
        }
    }

    __syncthreads();   // P dead; write normalized O into buf1 as [112][264]
    #pragma unroll
    for (int mt = 0; mt < 7; ++mt) {
        #pragma unroll
        for (int r = 0; r < 4; ++r) {
            float inv = 1.f / l_acc[mt][r];
            int srow = mt * 16 + lg * 4 + r;
            OL[srow * 264 + w * 32 + lr]      = f2bf(o_acc[mt][0][r] * inv);
            OL[srow * 264 + w * 32 + 16 + lr] = f2bf(o_acc[mt][1][r] * inv);
        }
    }
    __syncthreads();

    // o2 = OL @ wo_c^T + bo_c
    {
        f32x4 a2[7][2];
        #pragma unroll
        for (int mt = 0; mt < 7; ++mt)
            #pragma unroll
            for (int nt = 0; nt < 2; ++nt) { f32x4 z = {0.f,0.f,0.f,0.f}; a2[mt][nt] = z; }
        for (int ks = 0; ks < 8; ++ks) {
            int c0 = ks * 32;
            bf16x8 bw[2];
            #pragma unroll
            for (int nt = 0; nt < 2; ++nt)
                bw[nt] = *(const bf16x8*)(Wall + (size_t)(1792 + w * 32 + nt * 16 + lr) * 256 + c0 + lg * 8);
            #pragma unroll
            for (int mt = 0; mt < 7; ++mt) {
                bf16x8 af = *(const bf16x8*)(&OL[(mt * 16 + lr) * 264 + c0 + lg * 8]);
                a2[mt][0] = MFMA(af, bw[0], a2[mt][0]);
                a2[mt][1] = MFMA(af, bw[1], a2[mt][1]);
            }
        }
        #pragma unroll
        for (int mt = 0; mt < 7; ++mt)
            #pragma unroll
            for (int nt = 0; nt < 2; ++nt) {
                float bias = Ball[1792 + w * 32 + nt * 16 + lr];
                #pragma unroll
                for (int r = 0; r < 4; ++r) {
                    int srow = mt * 16 + lg * 4 + r;
                    O2[srow * 264 + w * 32 + nt * 16 + lr] = f2bf(a2[mt][nt][r] + bias);
                }
            }
    }
    __syncthreads();

    // h1 = relu(O2 @ w1^T + b1) -> OL
    {
        f32x4 a2[7][2];
        #pragma unroll
        for (int mt = 0; mt < 7; ++mt)
            #pragma unroll
            for (int nt = 0; nt < 2; ++nt) { f32x4 z = {0.f,0.f,0.f,0.f}; a2[mt][nt] = z; }
        for (int ks = 0; ks < 8; ++ks) {
            int c0 = ks * 32;
            bf16x8 bw[2];
            #pragma unroll
            for (int nt = 0; nt < 2; ++nt)
                bw[nt] = *(const bf16x8*)(Wall + (size_t)(2048 + w * 32 + nt * 16 + lr) * 256 + c0 + lg * 8);
            #pragma unroll
            for (int mt = 0; mt < 7; ++mt) {
                bf16x8 af = *(const bf16x8*)(&O2[(mt * 16 + lr) * 264 + c0 + lg * 8]);
                a2[mt][0] = MFMA(af, bw[0], a2[mt][0]);
                a2[mt][1] = MFMA(af, bw[1], a2[mt][1]);
            }
        }
        __syncthreads();   // all OL reads (oproj) finished before overwrite
        #pragma unroll
        for (int mt = 0; mt < 7; ++mt)
            #pragma unroll
            for (int nt = 0; nt < 2; ++nt) {
                float bias = Ball[2048 + w * 32 + nt * 16 + lr];
                #pragma unroll
                for (int r = 0; r < 4; ++r) {
                    int srow = mt * 16 + lg * 4 + r;
                    float v = a2[mt][nt][r] + bias;
                    v = v > 0.f ? v : 0.f;
                    OL[srow * 264 + w * 32 + nt * 16 + lr] = f2bf(v);
                }
            }
    }
    __syncthreads();

    // hbar[c] = mean_s<100 h1[s][c];  score partials from O2
    if (tid < 256) {
        float s = 0.f;
        for (int srow = 0; srow < 100; ++srow) s += bf2f(OL[srow * 264 + tid]);
        hbar[tid] = s * 0.01f;
    }
    if (tid < 100) {
        float s = 0.f;
        for (int c2 = 0; c2 < 256; ++c2)
            s += bf2f(O2[tid * 264 + c2]) * bf2f(Wall[(size_t)2336 * 256 + c2]);
        s += Ball[2336];
        scb[tid] = 1.f / (1.f + __expf(-s));
    }
    __syncthreads();
    if (tid < 32) {
        float s = 0.f;
        for (int c2 = 0; c2 < 256; ++c2)
            s += hbar[c2] * bf2f(Wall[(size_t)(2304 + tid) * 256 + c2]);
        s += Ball[2304 + tid];
        outp[(size_t)n * 32 + tid] = s;
    }
    if (tid == 64) {
        float s = 0.f;
        for (int i2 = 0; i2 < 100; ++i2) s += scb[i2];
        outp[16384 + n] = s * 0.01f;
    }
}

// ---------------------------------------------------------------------------
extern "C" void kernel_launch(void* const* d_in, const int* in_sizes, int n_in,
                              void* d_out, int out_size, void* d_ws, size_t ws_size,
                              hipStream_t stream)
{
    const float* features = (const float*)d_in[0];
    const float* qfeat    = (const float*)d_in[1];
    char* ws = (char*)d_ws;

    ushort* wbf  = (ushort*)ws;                    //  2337*256 bf16
    float*  bias = (float*)(ws + 1196544);         //  2337 f32
    ushort* qkv  = (ushort*)(ws + 1206016);        //  800*768
    ushort* sav  = (ushort*)(ws + 2434816);        //  800*256
    ushort* osb  = (ushort*)(ws + 2844416);        //  800*256
    ushort* qcp  = (ushort*)(ws + 3254016);        //  8*8*112*32
    ushort* kvb  = (ushort*)(ws + 3712768);

    prep_kernel<<<dim3(512), dim3(256), 0, stream>>>(
        (const float*)d_in[2], (const float*)d_in[3], (const float*)d_in[4],
        (const float*)d_in[8], (const float*)d_in[10], (const float*)d_in[11],
        (const float*)d_in[12], (const float*)d_in[16], (const float*)d_in[18],
        (const float*)d_in[20], (const float*)d_in[22],
        (const float*)d_in[5], (const float*)d_in[6], (const float*)d_in[7],
        (const float*)d_in[9], (const float*)d_in[13], (const float*)d_in[14],
        (const float*)d_in[15], (const float*)d_in[17], (const float*)d_in[19],
        (const float*)d_in[21], (const float*)d_in[23],
        wbf, bias, qcp);

    // self-attention chain
    gemm_rows<1, 100, 0><<<dim3(13, 6), dim3(256), 0, stream>>>(
        qfeat, wbf, bias, qkv, 800, 0, 0, 768);
    self_attn<<<dim3(64), dim3(128), 0, stream>>>(qkv, sav);
    gemm_rows<0, 1, 0><<<dim3(13, 2), dim3(256), 0, stream>>>(
        sav, wbf, bias, osb, 800, 768, 768, 256);
    gemm_rows<0, 1, 1><<<dim3(13, 2), dim3(256), 0, stream>>>(
        osb, wbf, bias, qcp, 800, 1024, 1024, 0);

    // cross-attention, pass-split on workspace budget
    const size_t per_n = 229376;               // bytes of kc+vc per proposal
    long avail = (long)ws_size - 3712768L;
    int Np = 512;
    if (avail < (long)(per_n * 512)) {
        Np = (int)(avail / (long)per_n);
        if (Np < 1) Np = 1;
    }
    ushort* kcb = kvb;                                   // [Np][224][256]
    ushort* vcb = kvb + (size_t)Np * 224 * 256;          // [Np][256][224]
    float* outp = (float*)d_out;
    for (int n0 = 0; n0 < 512; n0 += Np) {
        int cnt = (512 - n0 < Np) ? (512 - n0) : Np;
        kvproj<<<dim3(cnt, 2), dim3(512), 0, stream>>>(features, wbf, bias, kcb, vcb, n0);
        attn_fuse<<<dim3(cnt), dim3(512), 0, stream>>>(qcp, kcb, vcb, wbf, bias, outp, n0);
    }
}

// Round 4
// 259.669 us; speedup vs baseline: 1.5533x; 1.0435x over previous
//
#include <hip/hip_runtime.h>
#include <hip/hip_bf16.h>

// ---------------------------------------------------------------------------
// PolygonPredictionLayer: B=8,P=64,N=512,T=196(->224),S=100(->112),C=256,H=8,dh=32
// R4: kvproj v4 -- weight B-frags straight from global (L2), float4 feature
//     staging with conflict-free transpose, 64-t tiles (grid 512x4, 64 AGPR);
//     attn_fuse: T14 prefetch of next K/V chunk into registers.
// ---------------------------------------------------------------------------

typedef __attribute__((ext_vector_type(8))) short bf16x8;
typedef __attribute__((ext_vector_type(4))) float f32x4;

__device__ __forceinline__ float bf2f(ushort u) {
    union { float f; uint u32; } v; v.u32 = ((uint)u) << 16; return v.f;
}
__device__ __forceinline__ ushort f2bf(float f) {
    union { float f; uint u; } v; v.f = f;
    uint r = v.u + 0x7FFF + ((v.u >> 16) & 1);
    return (ushort)(r >> 16);
}
__device__ __forceinline__ f32x4 MFMA(bf16x8 a, bf16x8 b, f32x4 c) {
    return __builtin_amdgcn_mfma_f32_16x16x32_bf16(a, b, c, 0, 0, 0);
}

#define SCALE_DH 0.17677669529663687f  // 1/sqrt(32)

// ---------------- prep: weights+biases -> ws tables, qcp zero ---------------
#define TOTALW (2337 * 256)
#define QCPN   (8 * 8 * 112 * 32)
#define NBIAS  2337

__global__ void prep_kernel(const float* w0, const float* w1_, const float* w2_,
                            const float* w3, const float* w4, const float* w5,
                            const float* w6, const float* w7, const float* w8,
                            const float* w9, const float* w10,
                            const float* b0, const float* b1_, const float* b2_,
                            const float* b3, const float* b4, const float* b5,
                            const float* b6, const float* b7, const float* b8,
                            const float* b9, const float* b10,
                            ushort* wbf, float* bias, ushort* qcp)
{
    for (size_t i = blockIdx.x * blockDim.x + threadIdx.x;
         i < (size_t)TOTALW + QCPN + NBIAS; i += (size_t)gridDim.x * blockDim.x) {
        if (i < TOTALW) {
            int row = (int)(i >> 8), col = (int)(i & 255);
            const float* sp; int base;
            if      (row < 256)  { sp = w0;  base = 0; }
            else if (row < 512)  { sp = w1_; base = 256; }
            else if (row < 768)  { sp = w2_; base = 512; }
            else if (row < 1024) { sp = w3;  base = 768; }
            else if (row < 1280) { sp = w4;  base = 1024; }
            else if (row < 1536) { sp = w5;  base = 1280; }
            else if (row < 1792) { sp = w6;  base = 1536; }
            else if (row < 2048) { sp = w7;  base = 1792; }
            else if (row < 2304) { sp = w8;  base = 2048; }
            else if (row < 2336) { sp = w9;  base = 2304; }
            else                 { sp = w10; base = 2336; }
            wbf[i] = f2bf(sp[(size_t)(row - base) * 256 + col]);
        } else if (i < (size_t)TOTALW + QCPN) {
            qcp[i - TOTALW] = 0;
        } else {
            int idx = (int)(i - TOTALW - QCPN);
            const float* sp; int base;
            if      (idx < 256)  { sp = b0;  base = 0; }
            else if (idx < 512)  { sp = b1_; base = 256; }
            else if (idx < 768)  { sp = b2_; base = 512; }
            else if (idx < 1024) { sp = b3;  base = 768; }
            else if (idx < 1280) { sp = b4;  base = 1024; }
            else if (idx < 1536) { sp = b5;  base = 1280; }
            else if (idx < 1792) { sp = b6;  base = 1536; }
            else if (idx < 2048) { sp = b7;  base = 1792; }
            else if (idx < 2304) { sp = b8;  base = 2048; }
            else if (idx < 2336) { sp = b9;  base = 2304; }
            else                 { sp = b10; base = 2336; }
            bias[idx] = sp[idx - base];
        }
    }
}

// ---------------- generic small GEMM: out = A @ W^T + bias -----------------
template<int ASRC, int GS, int EPI>
__global__ __launch_bounds__(256)
void gemm_rows(const void* Aptr, const ushort* Wall, const float* Ball,
               ushort* Out, int M, int Wrow0, int Brow0, int ldo)
{
    __shared__ ushort As[64 * 40];
    __shared__ ushort Bs[128 * 40];
    int tid = threadIdx.x;
    int lane = tid & 63, w = tid >> 6;
    int lr = lane & 15, lg = lane >> 4;
    int r0 = blockIdx.x * 64;
    int j0 = blockIdx.y * 128;

    f32x4 acc[4][2];
    #pragma unroll
    for (int mt = 0; mt < 4; ++mt)
        #pragma unroll
        for (int nt = 0; nt < 2; ++nt) { f32x4 z = {0.f,0.f,0.f,0.f}; acc[mt][nt] = z; }

    for (int ks = 0; ks < 8; ++ks) {
        int c0 = ks * 32;
        {
            int i = tid >> 2, q = tid & 3;
            int r = r0 + i;
            if (ASRC == 0) {
                uint4 v = make_uint4(0u,0u,0u,0u);
                if (r < M) v = *(const uint4*)((const ushort*)Aptr + (size_t)r * 256 + c0 + q * 8);
                *(uint4*)(&As[i * 40 + q * 8]) = v;
            } else {
                uint u[4] = {0u,0u,0u,0u};
                if (r < M) {
                    int g = r / GS, o = r - g * GS;
                    const float* src = (const float*)Aptr + (size_t)g * 256 * GS + o;
                    #pragma unroll
                    for (int k2 = 0; k2 < 4; ++k2) {
                        ushort a0 = f2bf(src[(size_t)(c0 + q * 8 + 2 * k2)     * GS]);
                        ushort a1 = f2bf(src[(size_t)(c0 + q * 8 + 2 * k2 + 1) * GS]);
                        u[k2] = (uint)a0 | ((uint)a1 << 16);
                    }
                }
                *(uint4*)(&As[i * 40 + q * 8]) = make_uint4(u[0], u[1], u[2], u[3]);
            }
        }
        {
            int jj = tid >> 1, half = tid & 1;
            const ushort* src = Wall + (size_t)(Wrow0 + j0 + jj) * 256 + c0 + half * 16;
            ushort* dst = &Bs[jj * 40 + half * 16];
            *(uint4*)(dst)     = *(const uint4*)(src);
            *(uint4*)(dst + 8) = *(const uint4*)(src + 8);
        }
        __syncthreads();
        bf16x8 bfr[2];
        #pragma unroll
        for (int nt = 0; nt < 2; ++nt)
            bfr[nt] = *(const bf16x8*)(&Bs[(w * 32 + nt * 16 + lr) * 40 + lg * 8]);
        #pragma unroll
        for (int mt = 0; mt < 4; ++mt) {
            bf16x8 afr = *(const bf16x8*)(&As[(mt * 16 + lr) * 40 + lg * 8]);
            acc[mt][0] = MFMA(afr, bfr[0], acc[mt][0]);
            acc[mt][1] = MFMA(afr, bfr[1], acc[mt][1]);
        }
        __syncthreads();
    }
    #pragma unroll
    for (int mt = 0; mt < 4; ++mt) {
        #pragma unroll
        for (int nt = 0; nt < 2; ++nt) {
            int jc = j0 + w * 32 + nt * 16 + lr;
            float bias = Ball[Brow0 + jc];
            #pragma unroll
            for (int rg = 0; rg < 4; ++rg) {
                int r = r0 + mt * 16 + lg * 4 + rg;
                if (r >= M) continue;
                float vv = acc[mt][nt][rg] + bias;
                if (EPI == 0) {
                    Out[(size_t)r * ldo + jc] = f2bf(vv);
                } else {
                    int b = r / 100, s = r - b * 100;
                    int h = jc >> 5, d = jc & 31;
                    Out[(((size_t)(b * 8 + h)) * 112 + s) * 32 + d] = f2bf(vv * SCALE_DH);
                }
            }
        }
    }
}

// ---------------- self-attention (tiny, VALU) ------------------------------
__global__ __launch_bounds__(128)
void self_attn(const ushort* qkv, ushort* sav)
{
    __shared__ float kls[100][33];
    __shared__ float vls[100][33];
    __shared__ float sls[100][101];
    int bh = blockIdx.x; int b = bh >> 3, h = bh & 7;
    int tid = threadIdx.x;
    for (int idx = tid; idx < 100 * 32; idx += 128) {
        int t = idx >> 5, d = idx & 31;
        kls[t][d] = bf2f(qkv[((size_t)(b * 100 + t)) * 768 + 256 + h * 32 + d]);
        vls[t][d] = bf2f(qkv[((size_t)(b * 100 + t)) * 768 + 512 + h * 32 + d]);
    }
    __syncthreads();
    if (tid < 100) {
        int s = tid;
        float q[32];
        #pragma unroll
        for (int d = 0; d < 32; ++d)
            q[d] = bf2f(qkv[((size_t)(b * 100 + s)) * 768 + h * 32 + d]) * SCALE_DH;
        float mx = -1e30f;
        for (int t = 0; t < 100; ++t) {
            float sc = 0.f;
            #pragma unroll
            for (int d = 0; d < 32; ++d) sc += q[d] * kls[t][d];
            sls[s][t] = sc; mx = fmaxf(mx, sc);
        }
        float sum = 0.f;
        for (int t = 0; t < 100; ++t) {
            float p = __expf(sls[s][t] - mx);
            sls[s][t] = p; sum += p;
        }
        float inv = 1.f / sum;
        float acc2[32];
        #pragma unroll
        for (int d = 0; d < 32; ++d) acc2[d] = 0.f;
        for (int t = 0; t < 100; ++t) {
            float pv = sls[s][t];
            #pragma unroll
            for (int d = 0; d < 32; ++d) acc2[d] += pv * vls[t][d];
        }
        #pragma unroll
        for (int d = 0; d < 32; ++d)
            sav[((size_t)(b * 100 + s)) * 256 + h * 32 + d] = f2bf(acc2[d] * inv);
    }
}

// ---------------- kvproj v4: kc[n][224][256] t-major, vc[n][256][224] ------
// grid (cnt, 4 th), block 512 (8 waves); tile 64(t) x 512(K||V cout), K=256.
// Weights read straight from global (L2-resident); only feats^T tile in LDS.
__global__ __launch_bounds__(512)
void kvproj(const float* features, const ushort* Wall, const float* Ball,
            ushort* kc, ushort* vc, int n_base)
{
    __shared__ ushort As[64 * 40];
    int tid = threadIdx.x;
    int lane = tid & 63, w = tid >> 6;
    int lr = lane & 15, lg = lane >> 4;
    int nl = blockIdx.x;
    int n  = n_base + nl;
    int th = blockIdx.y;
    int t0 = th * 64;
    const float* fb = features + (size_t)n * 256 * 196;
    int sc = tid & 31, sq = tid >> 5;          // c-fast lane map (2-way max on LDS writes)
    int tg = t0 + sq * 4;
    // number of live mt tiles (t0+mt*16 < 224): th<3 -> 4, th==3 -> 2
    int mtmax = (th == 3) ? 2 : 4;

    f32x4 ak[4][2], av[4][2];
    #pragma unroll
    for (int mt = 0; mt < 4; ++mt)
        #pragma unroll
        for (int nt = 0; nt < 2; ++nt) {
            f32x4 z = {0.f,0.f,0.f,0.f}; ak[mt][nt] = z; av[mt][nt] = z;
        }

    for (int ks = 0; ks < 8; ++ks) {
        int c0 = ks * 32;
        __syncthreads();                       // protect As reads of prev kstep
        if (tg < 196) {                        // 196%4==0 -> float4 never straddles
            float4 v = *(const float4*)(fb + (size_t)(c0 + sc) * 196 + tg);
            As[(sq * 4 + 0) * 40 + sc] = f2bf(v.x);
            As[(sq * 4 + 1) * 40 + sc] = f2bf(v.y);
            As[(sq * 4 + 2) * 40 + sc] = f2bf(v.z);
            As[(sq * 4 + 3) * 40 + sc] = f2bf(v.w);
        } else {
            As[(sq * 4 + 0) * 40 + sc] = 0;
            As[(sq * 4 + 1) * 40 + sc] = 0;
            As[(sq * 4 + 2) * 40 + sc] = 0;
            As[(sq * 4 + 3) * 40 + sc] = 0;
        }
        __syncthreads();
        bf16x8 bk2[2], bv2[2];
        #pragma unroll
        for (int nt = 0; nt < 2; ++nt) {
            bk2[nt] = *(const bf16x8*)(Wall + (size_t)(1280 + w * 32 + nt * 16 + lr) * 256 + c0 + lg * 8);
            bv2[nt] = *(const bf16x8*)(Wall + (size_t)(1536 + w * 32 + nt * 16 + lr) * 256 + c0 + lg * 8);
        }
        #pragma unroll
        for (int mt = 0; mt < 4; ++mt) {
            if (mt < mtmax) {
                bf16x8 afr = *(const bf16x8*)(&As[(mt * 16 + lr) * 40 + lg * 8]);
                ak[mt][0] = MFMA(afr, bk2[0], ak[mt][0]);
                ak[mt][1] = MFMA(afr, bk2[1], ak[mt][1]);
                av[mt][0] = MFMA(afr, bv2[0], av[mt][0]);
                av[mt][1] = MFMA(afr, bv2[1], av[mt][1]);
            }
        }
    }
    #pragma unroll
    for (int mt = 0; mt < 4; ++mt) {
        if (mt >= mtmax) continue;
        #pragma unroll
        for (int nt = 0; nt < 2; ++nt) {
            int cout = w * 32 + nt * 16 + lr;
            float biask = Ball[1280 + cout];
            float biasv = Ball[1536 + cout];
            int tb = t0 + mt * 16 + lg * 4;
            // kc t-major
            #pragma unroll
            for (int rg = 0; rg < 4; ++rg)
                kc[((size_t)nl * 224 + tb + rg) * 256 + cout] = f2bf(ak[mt][nt][rg] + biask);
            // vc c-major, packed pairs along t
            size_t vb = ((size_t)nl * 256 + cout) * 224 + tb;
            uint v01 = (uint)f2bf(av[mt][nt][0] + biasv) | ((uint)f2bf(av[mt][nt][1] + biasv) << 16);
            uint v23 = (uint)f2bf(av[mt][nt][2] + biasv) | ((uint)f2bf(av[mt][nt][3] + biasv) << 16);
            *(uint*)(vc + vb)     = v01;
            *(uint*)(vc + vb + 2) = v23;
        }
    }
}

// ---------------- fused cross-attn + heads, one block per proposal ---------
// block 512 (8 waves, wave = head). T14: next chunk's K/V prefetched to regs.
// LDS: P[8][112][40] @0 (71680) | KCs[32][264] @71680 (16896) | VCs[256][40] @88576 (20480)
// epi: OL[112][264] @0 | O2[112][264] @71680 | hbar@59392 scb@60416
__global__ __launch_bounds__(512)
void attn_fuse(const ushort* qcp, const ushort* kc, const ushort* vc,
               const ushort* Wall, const float* Ball, float* outp, int n_base)
{
    __shared__ char smem[130816];
    ushort* P   = (ushort*)smem;
    ushort* KCs = (ushort*)(smem + 71680);
    ushort* VCs = (ushort*)(smem + 88576);
    ushort* OL  = (ushort*)smem;
    ushort* O2  = (ushort*)(smem + 71680);
    float* hbar = (float*)(smem + 59392);
    float* scb  = (float*)(smem + 60416);

    int tid = threadIdx.x;
    int lane = tid & 63; int w = tid >> 6;             // w = head
    int lr = lane & 15, lg = lane >> 4;
    int nl = blockIdx.x; int n = n_base + nl;
    int b = n >> 6;
    const ushort* kcn = kc + (size_t)nl * 224 * 256;
    const ushort* vcn = vc + (size_t)nl * 256 * 224;

    bf16x8 qf[7];
    #pragma unroll
    for (int mt = 0; mt < 7; ++mt)
        qf[mt] = *(const bf16x8*)(qcp + ((((size_t)(b * 8 + w)) * 112 + mt * 16 + lr) * 32 + lg * 8));

    bf16x8 ones;
    #pragma unroll
    for (int j = 0; j < 8; ++j) ones[j] = (short)0x3F80;   // bf16 1.0

    f32x4 o_acc[7][2], l_acc[7];
    #pragma unroll
    for (int mt = 0; mt < 7; ++mt) {
        f32x4 z = {0.f,0.f,0.f,0.f};
        o_acc[mt][0] = z; o_acc[mt][1] = z; l_acc[mt] = z;
    }

    // staging coords
    int kt = tid >> 4, kseg = tid & 15;        // K: [32 t][256 c]
    int vcc = tid >> 1, vhalf = tid & 1;       // V: [256 c][32 t]
    uint4 kr0, kr1, vr0, vr1;
    {   // prefetch chunk 0
        const ushort* s  = kcn + (size_t)kt * 256 + kseg * 16;
        const ushort* s2 = vcn + (size_t)vcc * 224 + vhalf * 16;
        kr0 = *(const uint4*)(s);  kr1 = *(const uint4*)(s + 8);
        vr0 = *(const uint4*)(s2); vr1 = *(const uint4*)(s2 + 8);
    }

    for (int ch = 0; ch < 7; ++ch) {
        int t0 = ch * 32;
        __syncthreads();   // prior chunk's KCs/VCs reads complete
        {   // regs -> LDS
            ushort* d  = &KCs[kt * 264 + kseg * 16];
            ushort* d2 = &VCs[vcc * 40 + vhalf * 16];
            *(uint4*)(d)      = kr0; *(uint4*)(d + 8)  = kr1;
            *(uint4*)(d2)     = vr0; *(uint4*)(d2 + 8) = vr1;
        }
        __syncthreads();
        if (ch < 6) {   // T14: issue next chunk loads, consumed after next barrier
            int t0n = t0 + 32;
            const ushort* s  = kcn + ((size_t)(t0n + kt)) * 256 + kseg * 16;
            const ushort* s2 = vcn + (size_t)vcc * 224 + t0n + vhalf * 16;
            kr0 = *(const uint4*)(s);  kr1 = *(const uint4*)(s + 8);
            vr0 = *(const uint4*)(s2); vr1 = *(const uint4*)(s2 + 8);
        }

        // QK^T: b[j] = K[t=nt*16+lr][d=w*32+lg*8+j]
        bf16x8 bk[2];
        #pragma unroll
        for (int nt = 0; nt < 2; ++nt)
            bk[nt] = *(const bf16x8*)(&KCs[(nt * 16 + lr) * 264 + w * 32 + lg * 8]);
        bool mask0 = (t0 + lr)      >= 196;
        bool mask1 = (t0 + 16 + lr) >= 196;
        #pragma unroll
        for (int mt = 0; mt < 7; ++mt) {
            f32x4 z = {0.f,0.f,0.f,0.f};
            f32x4 s0v = MFMA(qf[mt], bk[0], z);
            f32x4 s1v = MFMA(qf[mt], bk[1], z);
            #pragma unroll
            for (int r = 0; r < 4; ++r) {
                float p0 = mask0 ? 0.f : __expf(s0v[r]);
                float p1 = mask1 ? 0.f : __expf(s1v[r]);
                int srow = mt * 16 + lg * 4 + r;
                P[(w * 112 + srow) * 40 + lr]      = f2bf(p0);
                P[(w * 112 + srow) * 40 + 16 + lr] = f2bf(p1);
            }
        }
        // PV: b[j] = V[t=lg*8+j][c=w*32+nt*16+lr] from VCs[c][t]
        bf16x8 bv[2];
        #pragma unroll
        for (int nt = 0; nt < 2; ++nt)
            bv[nt] = *(const bf16x8*)(&VCs[(w * 32 + nt * 16 + lr) * 40 + lg * 8]);
        #pragma unroll
        for (int mt = 0; mt < 7; ++mt) {
            bf16x8 pf = *(const bf16x8*)(&P[(w * 112 + mt * 16 + lr) * 40 + lg * 8]);
            o_acc[mt][0] = MFMA(pf, bv[0], o_acc[mt][0]);
            o_acc[mt][1] = MFMA(pf, bv[1], o_acc[mt][1]);
            l_acc[mt]    = MFMA(pf, ones,  l_acc[mt]);
        }
    }

    __syncthreads();   // P dead; write normalized O into buf1 as [112][264]
    #pragma unroll
    for (int mt = 0; mt < 7; ++mt) {
        #pragma unroll
        for (int r = 0; r < 4; ++r) {
            float inv = 1.f / l_acc[mt][r];
            int srow = mt * 16 + lg * 4 + r;
            OL[srow * 264 + w * 32 + lr]      = f2bf(o_acc[mt][0][r] * inv);
            OL[srow * 264 + w * 32 + 16 + lr] = f2bf(o_acc[mt][1][r] * inv);
        }
    }
    __syncthreads();

    // o2 = OL @ wo_c^T + bo_c
    {
        f32x4 a2[7][2];
        #pragma unroll
        for (int mt = 0; mt < 7; ++mt)
            #pragma unroll
            for (int nt = 0; nt < 2; ++nt) { f32x4 z = {0.f,0.f,0.f,0.f}; a2[mt][nt] = z; }
        for (int ks = 0; ks < 8; ++ks) {
            int c0 = ks * 32;
            bf16x8 bw[2];
            #pragma unroll
            for (int nt = 0; nt < 2; ++nt)
                bw[nt] = *(const bf16x8*)(Wall + (size_t)(1792 + w * 32 + nt * 16 + lr) * 256 + c0 + lg * 8);
            #pragma unroll
            for (int mt = 0; mt < 7; ++mt) {
                bf16x8 af = *(const bf16x8*)(&OL[(mt * 16 + lr) * 264 + c0 + lg * 8]);
                a2[mt][0] = MFMA(af, bw[0], a2[mt][0]);
                a2[mt][1] = MFMA(af, bw[1], a2[mt][1]);
            }
        }
        #pragma unroll
        for (int mt = 0; mt < 7; ++mt)
            #pragma unroll
            for (int nt = 0; nt < 2; ++nt) {
                float bias = Ball[1792 + w * 32 + nt * 16 + lr];
                #pragma unroll
                for (int r = 0; r < 4; ++r) {
                    int srow = mt * 16 + lg * 4 + r;
                    O2[srow * 264 + w * 32 + nt * 16 + lr] = f2bf(a2[mt][nt][r] + bias);
                }
            }
    }
    __syncthreads();

    // h1 = relu(O2 @ w1^T + b1) -> OL
    {
        f32x4 a2[7][2];
        #pragma unroll
        for (int mt = 0; mt < 7; ++mt)
            #pragma unroll
            for (int nt = 0; nt < 2; ++nt) { f32x4 z = {0.f,0.f,0.f,0.f}; a2[mt][nt] = z; }
        for (int ks = 0; ks < 8; ++ks) {
            int c0 = ks * 32;
            bf16x8 bw[2];
            #pragma unroll
            for (int nt = 0; nt < 2; ++nt)
                bw[nt] = *(const bf16x8*)(Wall + (size_t)(2048 + w * 32 + nt * 16 + lr) * 256 + c0 + lg * 8);
            #pragma unroll
            for (int mt = 0; mt < 7; ++mt) {
                bf16x8 af = *(const bf16x8*)(&O2[(mt * 16 + lr) * 264 + c0 + lg * 8]);
                a2[mt][0] = MFMA(af, bw[0], a2[mt][0]);
                a2[mt][1] = MFMA(af, bw[1], a2[mt][1]);
            }
        }
        __syncthreads();   // all OL reads (oproj) finished before overwrite
        #pragma unroll
        for (int mt = 0; mt < 7; ++mt)
            #pragma unroll
            for (int nt = 0; nt < 2; ++nt) {
                float bias = Ball[2048 + w * 32 + nt * 16 + lr];
                #pragma unroll
                for (int r = 0; r < 4; ++r) {
                    int srow = mt * 16 + lg * 4 + r;
                    float v = a2[mt][nt][r] + bias;
                    v = v > 0.f ? v : 0.f;
                    OL[srow * 264 + w * 32 + nt * 16 + lr] = f2bf(v);
                }
            }
    }
    __syncthreads();

    // hbar[c] = mean_s<100 h1[s][c];  score partials from O2
    if (tid < 256) {
        float s = 0.f;
        for (int srow = 0; srow < 100; ++srow) s += bf2f(OL[srow * 264 + tid]);
        hbar[tid] = s * 0.01f;
    }
    if (tid < 100) {
        float s = 0.f;
        for (int c2 = 0; c2 < 256; ++c2)
            s += bf2f(O2[tid * 264 + c2]) * bf2f(Wall[(size_t)2336 * 256 + c2]);
        s += Ball[2336];
        scb[tid] = 1.f / (1.f + __expf(-s));
    }
    __syncthreads();
    if (tid < 32) {
        float s = 0.f;
        for (int c2 = 0; c2 < 256; ++c2)
            s += hbar[c2] * bf2f(Wall[(size_t)(2304 + tid) * 256 + c2]);
        s += Ball[2304 + tid];
        outp[(size_t)n * 32 + tid] = s;
    }
    if (tid == 64) {
        float s = 0.f;
        for (int i2 = 0; i2 < 100; ++i2) s += scb[i2];
        outp[16384 + n] = s * 0.01f;
    }
}

// ---------------------------------------------------------------------------
extern "C" void kernel_launch(void* const* d_in, const int* in_sizes, int n_in,
                              void* d_out, int out_size, void* d_ws, size_t ws_size,
                              hipStream_t stream)
{
    const float* features = (const float*)d_in[0];
    const float* qfeat    = (const float*)d_in[1];
    char* ws = (char*)d_ws;

    ushort* wbf  = (ushort*)ws;                    //  2337*256 bf16
    float*  bias = (float*)(ws + 1196544);         //  2337 f32
    ushort* qkv  = (ushort*)(ws + 1206016);        //  800*768
    ushort* sav  = (ushort*)(ws + 2434816);        //  800*256
    ushort* osb  = (ushort*)(ws + 2844416);        //  800*256
    ushort* qcp  = (ushort*)(ws + 3254016);        //  8*8*112*32
    ushort* kvb  = (ushort*)(ws + 3712768);

    prep_kernel<<<dim3(512), dim3(256), 0, stream>>>(
        (const float*)d_in[2], (const float*)d_in[3], (const float*)d_in[4],
        (const float*)d_in[8], (const float*)d_in[10], (const float*)d_in[11],
        (const float*)d_in[12], (const float*)d_in[16], (const float*)d_in[18],
        (const float*)d_in[20], (const float*)d_in[22],
        (const float*)d_in[5], (const float*)d_in[6], (const float*)d_in[7],
        (const float*)d_in[9], (const float*)d_in[13], (const float*)d_in[14],
        (const float*)d_in[15], (const float*)d_in[17], (const float*)d_in[19],
        (const float*)d_in[21], (const float*)d_in[23],
        wbf, bias, qcp);

    // self-attention chain
    gemm_rows<1, 100, 0><<<dim3(13, 6), dim3(256), 0, stream>>>(
        qfeat, wbf, bias, qkv, 800, 0, 0, 768);
    self_attn<<<dim3(64), dim3(128), 0, stream>>>(qkv, sav);
    gemm_rows<0, 1, 0><<<dim3(13, 2), dim3(256), 0, stream>>>(
        sav, wbf, bias, osb, 800, 768, 768, 256);
    gemm_rows<0, 1, 1><<<dim3(13, 2), dim3(256), 0, stream>>>(
        osb, wbf, bias, qcp, 800, 1024, 1024, 0);

    // cross-attention, pass-split on workspace budget
    const size_t per_n = 229376;               // bytes of kc+vc per proposal
    long avail = (long)ws_size - 3712768L;
    int Np = 512;
    if (avail < (long)(per_n * 512)) {
        Np = (int)(avail / (long)per_n);
        if (Np < 1) Np = 1;
    }
    ushort* kcb = kvb;                                   // [Np][224][256]
    ushort* vcb = kvb + (size_t)Np * 224 * 256;          // [Np][256][224]
    float* outp = (float*)d_out;
    for (int n0 = 0; n0 < 512; n0 += Np) {
        int cnt = (512 - n0 < Np) ? (512 - n0) : Np;
        kvproj<<<dim3(cnt, 4), dim3(512), 0, stream>>>(features, wbf, bias, kcb, vcb, n0);
        attn_fuse<<<dim3(cnt), dim3(512), 0, stream>>>(qcp, kcb, vcb, wbf, bias, outp, n0);
    }
}

// Round 5
// 230.411 us; speedup vs baseline: 1.7506x; 1.1270x over previous
//
#include <hip/hip_runtime.h>
#include <hip/hip_bf16.h>

// ---------------------------------------------------------------------------
// PolygonPredictionLayer: B=8,P=64,N=512,T=196(->224),S=100(->112),C=256,H=8,dh=32
// R5: kvproj v5 -- ONE barrier: block=proposal, full featT[224][264] bf16 in
//     LDS (118KB), weights held in 128 VGPR/wave (prefetched before staging),
//     then 14 t-tiles x 32 MFMA with no further sync. Outputs unchanged:
//     kc[n][224][256] t-major, vc[n][256][224] c-major.
// ---------------------------------------------------------------------------

typedef __attribute__((ext_vector_type(8))) short bf16x8;
typedef __attribute__((ext_vector_type(4))) float f32x4;

__device__ __forceinline__ float bf2f(ushort u) {
    union { float f; uint u32; } v; v.u32 = ((uint)u) << 16; return v.f;
}
__device__ __forceinline__ ushort f2bf(float f) {
    union { float f; uint u; } v; v.f = f;
    uint r = v.u + 0x7FFF + ((v.u >> 16) & 1);
    return (ushort)(r >> 16);
}
__device__ __forceinline__ f32x4 MFMA(bf16x8 a, bf16x8 b, f32x4 c) {
    return __builtin_amdgcn_mfma_f32_16x16x32_bf16(a, b, c, 0, 0, 0);
}

#define SCALE_DH 0.17677669529663687f  // 1/sqrt(32)

// ---------------- prep: weights+biases -> ws tables, qcp zero ---------------
#define TOTALW (2337 * 256)
#define QCPN   (8 * 8 * 112 * 32)
#define NBIAS  2337

__global__ void prep_kernel(const float* w0, const float* w1_, const float* w2_,
                            const float* w3, const float* w4, const float* w5,
                            const float* w6, const float* w7, const float* w8,
                            const float* w9, const float* w10,
                            const float* b0, const float* b1_, const float* b2_,
                            const float* b3, const float* b4, const float* b5,
                            const float* b6, const float* b7, const float* b8,
                            const float* b9, const float* b10,
                            ushort* wbf, float* bias, ushort* qcp)
{
    for (size_t i = blockIdx.x * blockDim.x + threadIdx.x;
         i < (size_t)TOTALW + QCPN + NBIAS; i += (size_t)gridDim.x * blockDim.x) {
        if (i < TOTALW) {
            int row = (int)(i >> 8), col = (int)(i & 255);
            const float* sp; int base;
            if      (row < 256)  { sp = w0;  base = 0; }
            else if (row < 512)  { sp = w1_; base = 256; }
            else if (row < 768)  { sp = w2_; base = 512; }
            else if (row < 1024) { sp = w3;  base = 768; }
            else if (row < 1280) { sp = w4;  base = 1024; }
            else if (row < 1536) { sp = w5;  base = 1280; }
            else if (row < 1792) { sp = w6;  base = 1536; }
            else if (row < 2048) { sp = w7;  base = 1792; }
            else if (row < 2304) { sp = w8;  base = 2048; }
            else if (row < 2336) { sp = w9;  base = 2304; }
            else                 { sp = w10; base = 2336; }
            wbf[i] = f2bf(sp[(size_t)(row - base) * 256 + col]);
        } else if (i < (size_t)TOTALW + QCPN) {
            qcp[i - TOTALW] = 0;
        } else {
            int idx = (int)(i - TOTALW - QCPN);
            const float* sp; int base;
            if      (idx < 256)  { sp = b0;  base = 0; }
            else if (idx < 512)  { sp = b1_; base = 256; }
            else if (idx < 768)  { sp = b2_; base = 512; }
            else if (idx < 1024) { sp = b3;  base = 768; }
            else if (idx < 1280) { sp = b4;  base = 1024; }
            else if (idx < 1536) { sp = b5;  base = 1280; }
            else if (idx < 1792) { sp = b6;  base = 1536; }
            else if (idx < 2048) { sp = b7;  base = 1792; }
            else if (idx < 2304) { sp = b8;  base = 2048; }
            else if (idx < 2336) { sp = b9;  base = 2304; }
            else                 { sp = b10; base = 2336; }
            bias[idx] = sp[idx - base];
        }
    }
}

// ---------------- generic small GEMM: out = A @ W^T + bias -----------------
template<int ASRC, int GS, int EPI>
__global__ __launch_bounds__(256)
void gemm_rows(const void* Aptr, const ushort* Wall, const float* Ball,
               ushort* Out, int M, int Wrow0, int Brow0, int ldo)
{
    __shared__ ushort As[64 * 40];
    __shared__ ushort Bs[128 * 40];
    int tid = threadIdx.x;
    int lane = tid & 63, w = tid >> 6;
    int lr = lane & 15, lg = lane >> 4;
    int r0 = blockIdx.x * 64;
    int j0 = blockIdx.y * 128;

    f32x4 acc[4][2];
    #pragma unroll
    for (int mt = 0; mt < 4; ++mt)
        #pragma unroll
        for (int nt = 0; nt < 2; ++nt) { f32x4 z = {0.f,0.f,0.f,0.f}; acc[mt][nt] = z; }

    for (int ks = 0; ks < 8; ++ks) {
        int c0 = ks * 32;
        {
            int i = tid >> 2, q = tid & 3;
            int r = r0 + i;
            if (ASRC == 0) {
                uint4 v = make_uint4(0u,0u,0u,0u);
                if (r < M) v = *(const uint4*)((const ushort*)Aptr + (size_t)r * 256 + c0 + q * 8);
                *(uint4*)(&As[i * 40 + q * 8]) = v;
            } else {
                uint u[4] = {0u,0u,0u,0u};
                if (r < M) {
                    int g = r / GS, o = r - g * GS;
                    const float* src = (const float*)Aptr + (size_t)g * 256 * GS + o;
                    #pragma unroll
                    for (int k2 = 0; k2 < 4; ++k2) {
                        ushort a0 = f2bf(src[(size_t)(c0 + q * 8 + 2 * k2)     * GS]);
                        ushort a1 = f2bf(src[(size_t)(c0 + q * 8 + 2 * k2 + 1) * GS]);
                        u[k2] = (uint)a0 | ((uint)a1 << 16);
                    }
                }
                *(uint4*)(&As[i * 40 + q * 8]) = make_uint4(u[0], u[1], u[2], u[3]);
            }
        }
        {
            int jj = tid >> 1, half = tid & 1;
            const ushort* src = Wall + (size_t)(Wrow0 + j0 + jj) * 256 + c0 + half * 16;
            ushort* dst = &Bs[jj * 40 + half * 16];
            *(uint4*)(dst)     = *(const uint4*)(src);
            *(uint4*)(dst + 8) = *(const uint4*)(src + 8);
        }
        __syncthreads();
        bf16x8 bfr[2];
        #pragma unroll
        for (int nt = 0; nt < 2; ++nt)
            bfr[nt] = *(const bf16x8*)(&Bs[(w * 32 + nt * 16 + lr) * 40 + lg * 8]);
        #pragma unroll
        for (int mt = 0; mt < 4; ++mt) {
            bf16x8 afr = *(const bf16x8*)(&As[(mt * 16 + lr) * 40 + lg * 8]);
            acc[mt][0] = MFMA(afr, bfr[0], acc[mt][0]);
            acc[mt][1] = MFMA(afr, bfr[1], acc[mt][1]);
        }
        __syncthreads();
    }
    #pragma unroll
    for (int mt = 0; mt < 4; ++mt) {
        #pragma unroll
        for (int nt = 0; nt < 2; ++nt) {
            int jc = j0 + w * 32 + nt * 16 + lr;
            float bias = Ball[Brow0 + jc];
            #pragma unroll
            for (int rg = 0; rg < 4; ++rg) {
                int r = r0 + mt * 16 + lg * 4 + rg;
                if (r >= M) continue;
                float vv = acc[mt][nt][rg] + bias;
                if (EPI == 0) {
                    Out[(size_t)r * ldo + jc] = f2bf(vv);
                } else {
                    int b = r / 100, s = r - b * 100;
                    int h = jc >> 5, d = jc & 31;
                    Out[(((size_t)(b * 8 + h)) * 112 + s) * 32 + d] = f2bf(vv * SCALE_DH);
                }
            }
        }
    }
}

// ---------------- self-attention (tiny, VALU) ------------------------------
__global__ __launch_bounds__(128)
void self_attn(const ushort* qkv, ushort* sav)
{
    __shared__ float kls[100][33];
    __shared__ float vls[100][33];
    __shared__ float sls[100][101];
    int bh = blockIdx.x; int b = bh >> 3, h = bh & 7;
    int tid = threadIdx.x;
    for (int idx = tid; idx < 100 * 32; idx += 128) {
        int t = idx >> 5, d = idx & 31;
        kls[t][d] = bf2f(qkv[((size_t)(b * 100 + t)) * 768 + 256 + h * 32 + d]);
        vls[t][d] = bf2f(qkv[((size_t)(b * 100 + t)) * 768 + 512 + h * 32 + d]);
    }
    __syncthreads();
    if (tid < 100) {
        int s = tid;
        float q[32];
        #pragma unroll
        for (int d = 0; d < 32; ++d)
            q[d] = bf2f(qkv[((size_t)(b * 100 + s)) * 768 + h * 32 + d]) * SCALE_DH;
        float mx = -1e30f;
        for (int t = 0; t < 100; ++t) {
            float sc = 0.f;
            #pragma unroll
            for (int d = 0; d < 32; ++d) sc += q[d] * kls[t][d];
            sls[s][t] = sc; mx = fmaxf(mx, sc);
        }
        float sum = 0.f;
        for (int t = 0; t < 100; ++t) {
            float p = __expf(sls[s][t] - mx);
            sls[s][t] = p; sum += p;
        }
        float inv = 1.f / sum;
        float acc2[32];
        #pragma unroll
        for (int d = 0; d < 32; ++d) acc2[d] = 0.f;
        for (int t = 0; t < 100; ++t) {
            float pv = sls[s][t];
            #pragma unroll
            for (int d = 0; d < 32; ++d) acc2[d] += pv * vls[t][d];
        }
        #pragma unroll
        for (int d = 0; d < 32; ++d)
            sav[((size_t)(b * 100 + s)) * 256 + h * 32 + d] = f2bf(acc2[d] * inv);
    }
}

// ---------------- kvproj v5: one block per proposal, one barrier -----------
// featT[224][264] bf16 in LDS (118272 B). Wave w holds weight frags for
// k-couts [32w,32w+32) and v-couts [32w,32w+32) in 128 VGPR; sweeps 14
// t-tiles: 8 ds_read_b128 (A) + 32 MFMA each. No sync after the single barrier.
__global__ __launch_bounds__(512, 2)
void kvproj(const float* features, const ushort* Wall, const float* Ball,
            ushort* kc, ushort* vc, int n_base)
{
    __shared__ ushort featT[224 * 264];
    int tid = threadIdx.x;
    int lane = tid & 63, w = tid >> 6;
    int lr = lane & 15, lg = lane >> 4;
    int nl = blockIdx.x;
    int n  = n_base + nl;
    const float* fb = features + (size_t)n * 256 * 196;

    // weight fragments: issue BEFORE staging so L2 latency hides under HBM burst
    // ct 0,1 = k rows 1280+w*32(+16); ct 2,3 = v rows 1536+w*32(+16)
    bf16x8 wf[4][8];
    #pragma unroll
    for (int ct = 0; ct < 4; ++ct) {
        int wrow = ((ct < 2) ? 1280 : 1536) + w * 32 + (ct & 1) * 16;
        #pragma unroll
        for (int ks = 0; ks < 8; ++ks)
            wf[ct][ks] = *(const bf16x8*)(Wall + (size_t)(wrow + lr) * 256 + ks * 32 + lg * 8);
    }
    float biask0 = Ball[1280 + w * 32 + lr];
    float biask1 = Ball[1296 + w * 32 + lr];
    float biasv0 = Ball[1536 + w * 32 + lr];
    float biasv1 = Ball[1552 + w * 32 + lr];

    // stage featT[t][c] = fb[c][t] (bf16), 12544 float4 loads, rotated writes
    for (int it = 0; it < 25; ++it) {
        int g = tid + it * 512;
        if (g < 12544) {                     // 256 c * 49 tq
            int c = g / 49, tq = g - c * 49;
            float4 v = *(const float4*)(fb + (size_t)c * 196 + tq * 4);
            float vv[4] = {v.x, v.y, v.z, v.w};
            #pragma unroll
            for (int i = 0; i < 4; ++i) {
                int j = (i + tq) & 3;        // rotate to spread write banks
                featT[(tq * 4 + j) * 264 + c] = f2bf(vv[j]);
            }
        }
    }
    for (int idx = tid; idx < 28 * 264; idx += 512)
        featT[196 * 264 + idx] = 0;          // zero pad rows 196..223
    __syncthreads();                          // the only barrier

    for (int tt = 0; tt < 14; ++tt) {
        bf16x8 af[8];
        #pragma unroll
        for (int ks = 0; ks < 8; ++ks)
            af[ks] = *(const bf16x8*)(&featT[(tt * 16 + lr) * 264 + ks * 32 + lg * 8]);
        f32x4 acc[4];
        #pragma unroll
        for (int ct = 0; ct < 4; ++ct) { f32x4 z = {0.f,0.f,0.f,0.f}; acc[ct] = z; }
        #pragma unroll
        for (int ks = 0; ks < 8; ++ks)
            #pragma unroll
            for (int ct = 0; ct < 4; ++ct)
                acc[ct] = MFMA(af[ks], wf[ct][ks], acc[ct]);

        int tb = tt * 16 + lg * 4;           // + rg; D: row=t(lg*4+rg), col=cout(lr)
        #pragma unroll
        for (int rg = 0; rg < 4; ++rg) {
            kc[((size_t)nl * 224 + tb + rg) * 256 + w * 32 + lr]      = f2bf(acc[0][rg] + biask0);
            kc[((size_t)nl * 224 + tb + rg) * 256 + w * 32 + 16 + lr] = f2bf(acc[1][rg] + biask1);
        }
        size_t vb0 = ((size_t)nl * 256 + w * 32 + lr) * 224 + tb;
        size_t vb1 = ((size_t)nl * 256 + w * 32 + 16 + lr) * 224 + tb;
        uint a01 = (uint)f2bf(acc[2][0] + biasv0) | ((uint)f2bf(acc[2][1] + biasv0) << 16);
        uint a23 = (uint)f2bf(acc[2][2] + biasv0) | ((uint)f2bf(acc[2][3] + biasv0) << 16);
        uint b01 = (uint)f2bf(acc[3][0] + biasv1) | ((uint)f2bf(acc[3][1] + biasv1) << 16);
        uint b23 = (uint)f2bf(acc[3][2] + biasv1) | ((uint)f2bf(acc[3][3] + biasv1) << 16);
        *(uint*)(vc + vb0)     = a01;
        *(uint*)(vc + vb0 + 2) = a23;
        *(uint*)(vc + vb1)     = b01;
        *(uint*)(vc + vb1 + 2) = b23;
    }
}

// ---------------- fused cross-attn + heads, one block per proposal ---------
// block 512 (8 waves, wave = head). T14: next chunk's K/V prefetched to regs.
// LDS: P[8][112][40] @0 (71680) | KCs[32][264] @71680 (16896) | VCs[256][40] @88576 (20480)
// epi: OL[112][264] @0 | O2[112][264] @71680 | hbar@59392 scb@60416
__global__ __launch_bounds__(512)
void attn_fuse(const ushort* qcp, const ushort* kc, const ushort* vc,
               const ushort* Wall, const float* Ball, float* outp, int n_base)
{
    __shared__ char smem[130816];
    ushort* P   = (ushort*)smem;
    ushort* KCs = (ushort*)(smem + 71680);
    ushort* VCs = (ushort*)(smem + 88576);
    ushort* OL  = (ushort*)smem;
    ushort* O2  = (ushort*)(smem + 71680);
    float* hbar = (float*)(smem + 59392);
    float* scb  = (float*)(smem + 60416);

    int tid = threadIdx.x;
    int lane = tid & 63; int w = tid >> 6;             // w = head
    int lr = lane & 15, lg = lane >> 4;
    int nl = blockIdx.x; int n = n_base + nl;
    int b = n >> 6;
    const ushort* kcn = kc + (size_t)nl * 224 * 256;
    const ushort* vcn = vc + (size_t)nl * 256 * 224;

    bf16x8 qf[7];
    #pragma unroll
    for (int mt = 0; mt < 7; ++mt)
        qf[mt] = *(const bf16x8*)(qcp + ((((size_t)(b * 8 + w)) * 112 + mt * 16 + lr) * 32 + lg * 8));

    bf16x8 ones;
    #pragma unroll
    for (int j = 0; j < 8; ++j) ones[j] = (short)0x3F80;   // bf16 1.0

    f32x4 o_acc[7][2], l_acc[7];
    #pragma unroll
    for (int mt = 0; mt < 7; ++mt) {
        f32x4 z = {0.f,0.f,0.f,0.f};
        o_acc[mt][0] = z; o_acc[mt][1] = z; l_acc[mt] = z;
    }

    // staging coords
    int kt = tid >> 4, kseg = tid & 15;        // K: [32 t][256 c]
    int vcc = tid >> 1, vhalf = tid & 1;       // V: [256 c][32 t]
    uint4 kr0, kr1, vr0, vr1;
    {   // prefetch chunk 0
        const ushort* s  = kcn + (size_t)kt * 256 + kseg * 16;
        const ushort* s2 = vcn + (size_t)vcc * 224 + vhalf * 16;
        kr0 = *(const uint4*)(s);  kr1 = *(const uint4*)(s + 8);
        vr0 = *(const uint4*)(s2); vr1 = *(const uint4*)(s2 + 8);
    }

    for (int ch = 0; ch < 7; ++ch) {
        int t0 = ch * 32;
        __syncthreads();   // prior chunk's KCs/VCs reads complete
        {   // regs -> LDS
            ushort* d  = &KCs[kt * 264 + kseg * 16];
            ushort* d2 = &VCs[vcc * 40 + vhalf * 16];
            *(uint4*)(d)      = kr0; *(uint4*)(d + 8)  = kr1;
            *(uint4*)(d2)     = vr0; *(uint4*)(d2 + 8) = vr1;
        }
        __syncthreads();
        if (ch < 6) {   // T14: issue next chunk loads, consumed after next barrier
            int t0n = t0 + 32;
            const ushort* s  = kcn + ((size_t)(t0n + kt)) * 256 + kseg * 16;
            const ushort* s2 = vcn + (size_t)vcc * 224 + t0n + vhalf * 16;
            kr0 = *(const uint4*)(s);  kr1 = *(const uint4*)(s + 8);
            vr0 = *(const uint4*)(s2); vr1 = *(const uint4*)(s2 + 8);
        }

        // QK^T: b[j] = K[t=nt*16+lr][d=w*32+lg*8+j]
        bf16x8 bk[2];
        #pragma unroll
        for (int nt = 0; nt < 2; ++nt)
            bk[nt] = *(const bf16x8*)(&KCs[(nt * 16 + lr) * 264 + w * 32 + lg * 8]);
        bool mask0 = (t0 + lr)      >= 196;
        bool mask1 = (t0 + 16 + lr) >= 196;
        #pragma unroll
        for (int mt = 0; mt < 7; ++mt) {
            f32x4 z = {0.f,0.f,0.f,0.f};
            f32x4 s0v = MFMA(qf[mt], bk[0], z);
            f32x4 s1v = MFMA(qf[mt], bk[1], z);
            #pragma unroll
            for (int r = 0; r < 4; ++r) {
                float p0 = mask0 ? 0.f : __expf(s0v[r]);
                float p1 = mask1 ? 0.f : __expf(s1v[r]);
                int srow = mt * 16 + lg * 4 + r;
                P[(w * 112 + srow) * 40 + lr]      = f2bf(p0);
                P[(w * 112 + srow) * 40 + 16 + lr] = f2bf(p1);
            }
        }
        // PV: b[j] = V[t=lg*8+j][c=w*32+nt*16+lr] from VCs[c][t]
        bf16x8 bv[2];
        #pragma unroll
        for (int nt = 0; nt < 2; ++nt)
            bv[nt] = *(const bf16x8*)(&VCs[(w * 32 + nt * 16 + lr) * 40 + lg * 8]);
        #pragma unroll
        for (int mt = 0; mt < 7; ++mt) {
            bf16x8 pf = *(const bf16x8*)(&P[(w * 112 + mt * 16 + lr) * 40 + lg * 8]);
            o_acc[mt][0] = MFMA(pf, bv[0], o_acc[mt][0]);
            o_acc[mt][1] = MFMA(pf, bv[1], o_acc[mt][1]);
            l_acc[mt]    = MFMA(pf, ones,  l_acc[mt]);
        }
    }

    __syncthreads();   // P dead; write normalized O into buf1 as [112][264]
    #pragma unroll
    for (int mt = 0; mt < 7; ++mt) {
        #pragma unroll
        for (int r = 0; r < 4; ++r) {
            float inv = 1.f / l_acc[mt][r];
            int srow = mt * 16 + lg * 4 + r;
            OL[srow * 264 + w * 32 + lr]      = f2bf(o_acc[mt][0][r] * inv);
            OL[srow * 264 + w * 32 + 16 + lr] = f2bf(o_acc[mt][1][r] * inv);
        }
    }
    __syncthreads();

    // o2 = OL @ wo_c^T + bo_c
    {
        f32x4 a2[7][2];
        #pragma unroll
        for (int mt = 0; mt < 7; ++mt)
            #pragma unroll
            for (int nt = 0; nt < 2; ++nt) { f32x4 z = {0.f,0.f,0.f,0.f}; a2[mt][nt] = z; }
        for (int ks = 0; ks < 8; ++ks) {
            int c0 = ks * 32;
            bf16x8 bw[2];
            #pragma unroll
            for (int nt = 0; nt < 2; ++nt)
                bw[nt] = *(const bf16x8*)(Wall + (size_t)(1792 + w * 32 + nt * 16 + lr) * 256 + c0 + lg * 8);
            #pragma unroll
            for (int mt = 0; mt < 7; ++mt) {
                bf16x8 af = *(const bf16x8*)(&OL[(mt * 16 + lr) * 264 + c0 + lg * 8]);
                a2[mt][0] = MFMA(af, bw[0], a2[mt][0]);
                a2[mt][1] = MFMA(af, bw[1], a2[mt][1]);
            }
        }
        #pragma unroll
        for (int mt = 0; mt < 7; ++mt)
            #pragma unroll
            for (int nt = 0; nt < 2; ++nt) {
                float bias = Ball[1792 + w * 32 + nt * 16 + lr];
                #pragma unroll
                for (int r = 0; r < 4; ++r) {
                    int srow = mt * 16 + lg * 4 + r;
                    O2[srow * 264 + w * 32 + nt * 16 + lr] = f2bf(a2[mt][nt][r] + bias);
                }
            }
    }
    __syncthreads();

    // h1 = relu(O2 @ w1^T + b1) -> OL
    {
        f32x4 a2[7][2];
        #pragma unroll
        for (int mt = 0; mt < 7; ++mt)
            #pragma unroll
            for (int nt = 0; nt < 2; ++nt) { f32x4 z = {0.f,0.f,0.f,0.f}; a2[mt][nt] = z; }
        for (int ks = 0; ks < 8; ++ks) {
            int c0 = ks * 32;
            bf16x8 bw[2];
            #pragma unroll
            for (int nt = 0; nt < 2; ++nt)
                bw[nt] = *(const bf16x8*)(Wall + (size_t)(2048 + w * 32 + nt * 16 + lr) * 256 + c0 + lg * 8);
            #pragma unroll
            for (int mt = 0; mt < 7; ++mt) {
                bf16x8 af = *(const bf16x8*)(&O2[(mt * 16 + lr) * 264 + c0 + lg * 8]);
                a2[mt][0] = MFMA(af, bw[0], a2[mt][0]);
                a2[mt][1] = MFMA(af, bw[1], a2[mt][1]);
            }
        }
        __syncthreads();   // all OL reads (oproj) finished before overwrite
        #pragma unroll
        for (int mt = 0; mt < 7; ++mt)
            #pragma unroll
            for (int nt = 0; nt < 2; ++nt) {
                float bias = Ball[2048 + w * 32 + nt * 16 + lr];
                #pragma unroll
                for (int r = 0; r < 4; ++r) {
                    int srow = mt * 16 + lg * 4 + r;
                    float v = a2[mt][nt][r] + bias;
                    v = v > 0.f ? v : 0.f;
                    OL[srow * 264 + w * 32 + nt * 16 + lr] = f2bf(v);
                }
            }
    }
    __syncthreads();

    // hbar[c] = mean_s<100 h1[s][c];  score partials from O2
    if (tid < 256) {
        float s = 0.f;
        for (int srow = 0; srow < 100; ++srow) s += bf2f(OL[srow * 264 + tid]);
        hbar[tid] = s * 0.01f;
    }
    if (tid < 100) {
        float s = 0.f;
        for (int c2 = 0; c2 < 256; ++c2)
            s += bf2f(O2[tid * 264 + c2]) * bf2f(Wall[(size_t)2336 * 256 + c2]);
        s += Ball[2336];
        scb[tid] = 1.f / (1.f + __expf(-s));
    }
    __syncthreads();
    if (tid < 32) {
        float s = 0.f;
        for (int c2 = 0; c2 < 256; ++c2)
            s += hbar[c2] * bf2f(Wall[(size_t)(2304 + tid) * 256 + c2]);
        s += Ball[2304 + tid];
        outp[(size_t)n * 32 + tid] = s;
    }
    if (tid == 64) {
        float s = 0.f;
        for (int i2 = 0; i2 < 100; ++i2) s += scb[i2];
        outp[16384 + n] = s * 0.01f;
    }
}

// ---------------------------------------------------------------------------
extern "C" void kernel_launch(void* const* d_in, const int* in_sizes, int n_in,
                              void* d_out, int out_size, void* d_ws, size_t ws_size,
                              hipStream_t stream)
{
    const float* features = (const float*)d_in[0];
    const float* qfeat    = (const float*)d_in[1];
    char* ws = (char*)d_ws;

    ushort* wbf  = (ushort*)ws;                    //  2337*256 bf16
    float*  bias = (float*)(ws + 1196544);         //  2337 f32
    ushort* qkv  = (ushort*)(ws + 1206016);        //  800*768
    ushort* sav  = (ushort*)(ws + 2434816);        //  800*256
    ushort* osb  = (ushort*)(ws + 2844416);        //  800*256
    ushort* qcp  = (ushort*)(ws + 3254016);        //  8*8*112*32
    ushort* kvb  = (ushort*)(ws + 3712768);

    prep_kernel<<<dim3(512), dim3(256), 0, stream>>>(
        (const float*)d_in[2], (const float*)d_in[3], (const float*)d_in[4],
        (const float*)d_in[8], (const float*)d_in[10], (const float*)d_in[11],
        (const float*)d_in[12], (const float*)d_in[16], (const float*)d_in[18],
        (const float*)d_in[20], (const float*)d_in[22],
        (const float*)d_in[5], (const float*)d_in[6], (const float*)d_in[7],
        (const float*)d_in[9], (const float*)d_in[13], (const float*)d_in[14],
        (const float*)d_in[15], (const float*)d_in[17], (const float*)d_in[19],
        (const float*)d_in[21], (const float*)d_in[23],
        wbf, bias, qcp);

    // self-attention chain
    gemm_rows<1, 100, 0><<<dim3(13, 6), dim3(256), 0, stream>>>(
        qfeat, wbf, bias, qkv, 800, 0, 0, 768);
    self_attn<<<dim3(64), dim3(128), 0, stream>>>(qkv, sav);
    gemm_rows<0, 1, 0><<<dim3(13, 2), dim3(256), 0, stream>>>(
        sav, wbf, bias, osb, 800, 768, 768, 256);
    gemm_rows<0, 1, 1><<<dim3(13, 2), dim3(256), 0, stream>>>(
        osb, wbf, bias, qcp, 800, 1024, 1024, 0);

    // cross-attention, pass-split on workspace budget
    const size_t per_n = 229376;               // bytes of kc+vc per proposal
    long avail = (long)ws_size - 3712768L;
    int Np = 512;
    if (avail < (long)(per_n * 512)) {
        Np = (int)(avail / (long)per_n);
        if (Np < 1) Np = 1;
    }
    ushort* kcb = kvb;                                   // [Np][224][256]
    ushort* vcb = kvb + (size_t)Np * 224 * 256;          // [Np][256][224]
    float* outp = (float*)d_out;
    for (int n0 = 0; n0 < 512; n0 += Np) {
        int cnt = (512 - n0 < Np) ? (512 - n0) : Np;
        kvproj<<<dim3(cnt), dim3(512), 0, stream>>>(features, wbf, bias, kcb, vcb, n0);
        attn_fuse<<<dim3(cnt), dim3(512), 0, stream>>>(qcp, kcb, vcb, wbf, bias, outp, n0);
    }
}